// Round 2
// baseline (256.991 us; speedup 1.0000x reference)
//
#include <hip/hip_runtime.h>
#include <hip/hip_bf16.h>
#include <stdint.h>

typedef _Float16 half8 __attribute__((ext_vector_type(8)));
typedef _Float16 half4 __attribute__((ext_vector_type(4)));
typedef float    f32x4 __attribute__((ext_vector_type(4)));

#define MFMA16(a, b, c) __builtin_amdgcn_mfma_f32_16x16x32_f16(a, b, c, 0, 0, 0)

// ---------------------------------------------------------------------------
// Generic fp32->fp16 transpose: X [R][C] fp32 -> Y [C][R] fp16, z-batched.
// ---------------------------------------------------------------------------
__global__ __launch_bounds__(256) void transpose_to_f16(
    const float* __restrict__ X, _Float16* __restrict__ Y,
    int R, int C, long inBS, long outBS)
{
    __shared__ float t[32][33];
    const int bz = blockIdx.z;
    X += (long)bz * inBS;
    Y += (long)bz * outBS;
    const int c0 = blockIdx.x * 32, r0 = blockIdx.y * 32;
    const int tx = threadIdx.x & 31, ty = threadIdx.x >> 5;
#pragma unroll
    for (int i = 0; i < 4; ++i)
        t[ty + i * 8][tx] = X[(long)(r0 + ty + i * 8) * C + c0 + tx];
    __syncthreads();
#pragma unroll
    for (int i = 0; i < 4; ++i)
        Y[(long)(c0 + ty + i * 8) * R + r0 + tx] = (_Float16)t[tx][ty + i * 8];
}

// ---------------------------------------------------------------------------
// MFMA GEMM v4. C = A(fp32) @ BT(fp16).
// R1 post-mortem: VGPR_Count=76 proved the compiler SANK the prefetch loads
// to their use site (a live prefetch needs ~130 VGPRs: 64 acc + 48 in-flight),
// so every K-step still exposed full load latency (MfmaUtil 14.7%).
// R2 change: __builtin_amdgcn_sched_barrier(0) pins the prefetch issue BEFORE
// the MFMA phase. Loads' only consumer (STORE_LDS) is after the next barrier,
// so their L2 latency hides under the ~1000-cyc/SIMD MFMA phase; the
// compiler's vmcnt(0) drain at the closing __syncthreads is exactly where the
// data is needed. Litmus for success: VGPR_Count jumps to ~120-140.
// ---------------------------------------------------------------------------
__global__ __launch_bounds__(256, 2) void gemm_f16_v2(
    const float* __restrict__ A0, const float* __restrict__ A1,
    const _Float16* __restrict__ BT,
    const float* __restrict__ bias0, const float* __restrict__ bias1,
    void* __restrict__ Cout,
    int N, int lda, int ldbt, int ldc,
    long aBS, long bBS, long cBS,
    int c_half, int atomic, int nks, int kchunk)
{
    __shared__ __align__(16) _Float16 As[128][72];
    __shared__ __align__(16) _Float16 Bs[128][72];

    // --- XCD-aware bijective swizzle (m204 variant), decode x-fastest ---
    const int gx  = gridDim.x, gy = gridDim.y;
    const int nwg = gx * gy * (int)gridDim.z;
    const int lid = (int)blockIdx.x + gx * ((int)blockIdx.y + gy * (int)blockIdx.z);
    const int q8  = nwg >> 3, r8 = nwg & 7;
    const int xcd = lid & 7, loc = lid >> 3;
    const int sw  = (xcd < r8 ? xcd * (q8 + 1) : r8 * (q8 + 1) + (xcd - r8) * q8) + loc;
    const int nt  = sw % gx;
    const int tm2 = sw / gx;
    const int mt  = tm2 % gy;
    const int bz  = tm2 / gy;

    const int b = bz / nks, ks = bz % nks;
    const int kbeg = ks * kchunk;
    const int kend = kbeg + kchunk;

    const float* A = A1 ? (b ? A1 : A0) : (A0 + (long)b * aBS);
    const _Float16* Bb = BT + (long)b * bBS;

    const int n0 = nt * 128;
    const int m0 = mt * 128;
    const int tid  = threadIdx.x;
    const int wave = tid >> 6, lane = tid & 63;
    const int m16  = lane & 15, quad = lane >> 4;

    // staging roles
    const int acol = (tid & 15) * 4;   // A: k-col within tile (x4 fp32)
    const int arb  = tid >> 4;         // A: row base 0..15 (+p*16)
    const int bj   = tid >> 1;         // B: row (n) 0..127
    const int bcc  = (tid & 1) * 32;   // B: k-col chunk
    int jn = n0 + bj; if (jn > N - 1) jn = N - 1;
    const _Float16* bpB = Bb + (long)jn * ldbt;

    f32x4 acc[2][8];
    {
        f32x4 z = {0.f, 0.f, 0.f, 0.f};
#pragma unroll
        for (int i = 0; i < 2; ++i)
#pragma unroll
            for (int j = 0; j < 8; ++j) acc[i][j] = z;
    }

    // prefetch registers (ext_vector types -> clean VGPR tuples)
    f32x4 av[8];
    half8 bv0, bv1, bv2, bv3;

    auto LOADT = [&](int k0) {
#pragma unroll
        for (int p = 0; p < 8; ++p)
            av[p] = *(const f32x4*)(A + (long)(m0 + arb + p * 16) * lda + k0 + acol);
        const _Float16* bp = bpB + k0 + bcc;
        bv0 = *(const half8*)(bp);
        bv1 = *(const half8*)(bp + 8);
        bv2 = *(const half8*)(bp + 16);
        bv3 = *(const half8*)(bp + 24);
    };
    auto STORE_LDS = [&]() {
#pragma unroll
        for (int p = 0; p < 8; ++p) {
            half4 hv;
            hv[0] = (_Float16)av[p][0]; hv[1] = (_Float16)av[p][1];
            hv[2] = (_Float16)av[p][2]; hv[3] = (_Float16)av[p][3];
            *(half4*)&As[arb + p * 16][acol] = hv;
        }
        *(half8*)&Bs[bj][bcc]      = bv0;
        *(half8*)&Bs[bj][bcc + 8]  = bv1;
        *(half8*)&Bs[bj][bcc + 16] = bv2;
        *(half8*)&Bs[bj][bcc + 24] = bv3;
    };

    LOADT(kbeg);
    for (int k0 = kbeg; k0 < kend; k0 += 64) {
        STORE_LDS();
        __syncthreads();                       // tile visible to all waves
        if (k0 + 64 < kend) LOADT(k0 + 64);    // issue next tile's loads...
        // ...and PIN them before the MFMA phase so the scheduler cannot sink
        // them to their use site (R1 failure mode). Their latency now hides
        // under the MFMAs; the closing __syncthreads' vmcnt(0) drain is
        // exactly where they must have landed.
        __builtin_amdgcn_sched_barrier(0);
#pragma unroll
        for (int kss = 0; kss < 2; ++kss) {
            const int ko = kss * 32 + quad * 8;
            const half8 a0 = *(const half8*)&As[wave * 32 + m16][ko];
            const half8 a1 = *(const half8*)&As[wave * 32 + 16 + m16][ko];
#pragma unroll
            for (int c = 0; c < 8; ++c) {
                const half8 bf = *(const half8*)&Bs[c * 16 + m16][ko];
                acc[0][c] = MFMA16(a0, bf, acc[0][c]);
                acc[1][c] = MFMA16(a1, bf, acc[1][c]);
            }
        }
        __syncthreads();                       // compute done; safe to restage
    }

    const float* bias = b ? bias1 : bias0;
    const int addb = (bias != nullptr) && (kbeg == 0);
#pragma unroll
    for (int hh = 0; hh < 2; ++hh) {
#pragma unroll
        for (int c = 0; c < 8; ++c) {
            const int col = n0 + c * 16 + m16;
            if (col >= N) continue;
            const float bb = addb ? bias[col] : 0.f;
#pragma unroll
            for (int r = 0; r < 4; ++r) {
                const int row = m0 + wave * 32 + hh * 16 + quad * 4 + r;
                const float v = acc[hh][c][r] + bb;
                const long idx = (long)b * cBS + (long)row * ldc + col;
                if (atomic)      atomicAdd(&((float*)Cout)[idx], v);
                else if (c_half) ((_Float16*)Cout)[idx] = (_Float16)v;
                else             ((float*)Cout)[idx] = v;
            }
        }
    }
}

// ---------------------------------------------------------------------------
// Pass 1 v3: per (b,h,s) row stats — LDS-staged (unchanged this round).
// ---------------------------------------------------------------------------
__global__ __launch_bounds__(256, 2) void attn_stats(
    const _Float16* __restrict__ q_all, const _Float16* __restrict__ k_all,
    float* __restrict__ m_out, float* __restrict__ il_out)
{
    const int st = blockIdx.x, h = blockIdx.y, b = blockIdx.z;
    const int tid = threadIdx.x, wave = tid >> 6, lane = tid & 63;
    const int m16 = lane & 15, quad = lane >> 4;
    const int s0 = st * 64;
    const int sw = s0 + wave * 16;

    __shared__ __align__(16) _Float16 qs[64][72];
    __shared__ __align__(16) _Float16 ks[64][72];

    const int srow = tid >> 2;              // 0..63
    const int scol = (tid & 3) * 16;        // halves: 0,16,32,48

    {
        const _Float16* qsrc = q_all + ((long)(b * 1024 + s0 + srow)) * 1024 + h * 64 + scol;
        *(half8*)&qs[srow][scol]     = *(const half8*)(qsrc);
        *(half8*)&qs[srow][scol + 8] = *(const half8*)(qsrc + 8);
    }

    const _Float16* ksrcb = k_all + ((long)(b * 1024 + srow)) * 1024 + h * 64 + scol;

    float mr[4], lr[4];
#pragma unroll
    for (int r = 0; r < 4; ++r) { mr[r] = -3.0e38f; lr[r] = 0.f; }

    half8 a0, a1;
    for (int tt = 0; tt <= st; ++tt) {
        const _Float16* ksrc = ksrcb + (long)(tt * 64) * 1024;
        const half8 k0 = *(const half8*)(ksrc);
        const half8 k1 = *(const half8*)(ksrc + 8);

        __syncthreads();
        *(half8*)&ks[srow][scol]     = k0;
        *(half8*)&ks[srow][scol + 8] = k1;
        __syncthreads();

        if (tt == 0) {
            a0 = *(const half8*)&qs[wave * 16 + m16][quad * 8];
            a1 = *(const half8*)&qs[wave * 16 + m16][quad * 8 + 32];
        }

        if (tt < st) {
#pragma unroll
            for (int c = 0; c < 4; ++c) {
                const half8 b0 = *(const half8*)&ks[c * 16 + m16][quad * 8];
                const half8 b1 = *(const half8*)&ks[c * 16 + m16][quad * 8 + 32];
                f32x4 cc = {0.f, 0.f, 0.f, 0.f};
                cc = MFMA16(a0, b0, cc);
                cc = MFMA16(a1, b1, cc);
#pragma unroll
                for (int r = 0; r < 4; ++r) {
                    const float z  = cc[r] * 0.125f;
                    const float nm = fmaxf(mr[r], z);
                    lr[r] = lr[r] * __expf(mr[r] - nm) + __expf(z - nm);
                    mr[r] = nm;
                }
            }
        } else {
#pragma unroll
            for (int c = 0; c < 4; ++c) {
                const half8 b0 = *(const half8*)&ks[c * 16 + m16][quad * 8];
                const half8 b1 = *(const half8*)&ks[c * 16 + m16][quad * 8 + 32];
                f32x4 cc = {0.f, 0.f, 0.f, 0.f};
                cc = MFMA16(a0, b0, cc);
                cc = MFMA16(a1, b1, cc);
                const int col = tt * 64 + c * 16 + m16;
#pragma unroll
                for (int r = 0; r < 4; ++r) {
                    const int row = sw + quad * 4 + r;
                    if (col <= row) {
                        const float z  = cc[r] * 0.125f;
                        const float nm = fmaxf(mr[r], z);
                        lr[r] = lr[r] * __expf(mr[r] - nm) + __expf(z - nm);
                        mr[r] = nm;
                    }
                }
            }
        }
    }

#pragma unroll
    for (int mk = 1; mk < 16; mk <<= 1) {
#pragma unroll
        for (int r = 0; r < 4; ++r) {
            const float om = __shfl_xor(mr[r], mk);
            const float ol = __shfl_xor(lr[r], mk);
            const float nm = fmaxf(mr[r], om);
            lr[r] = lr[r] * __expf(mr[r] - nm) + ol * __expf(om - nm);
            mr[r] = nm;
        }
    }
    if (m16 == 0) {
#pragma unroll
        for (int r = 0; r < 4; ++r) {
            const long idx = ((long)(b * 16 + h)) * 1024 + sw + quad * 4 + r;
            m_out[idx]  = mr[r];
            il_out[idx] = 1.f / lr[r];
        }
    }
}

// ---------------------------------------------------------------------------
// Pass 2 v4: attn_mean = (1/H) sum_h softmax — LDS-staged (unchanged).
// ---------------------------------------------------------------------------
__global__ __launch_bounds__(256, 2) void attn_pmean(
    const _Float16* __restrict__ q_all, const _Float16* __restrict__ k_all,
    const float* __restrict__ m_in, const float* __restrict__ il_in,
    float* __restrict__ attn)
{
    const int ttile = blockIdx.x, stile = blockIdx.y, b = blockIdx.z;
    const int tid = threadIdx.x;
    if (ttile > stile) {
        const int c4 = (tid & 15) * 4;
        float4 z = {0.f, 0.f, 0.f, 0.f};
#pragma unroll
        for (int i = 0; i < 4; ++i) {
            const int r = stile * 64 + (tid >> 4) + i * 16;
            *(float4*)&attn[((long)(b * 1024 + r)) * 1024 + ttile * 64 + c4] = z;
        }
        return;
    }

    __shared__ __align__(16) _Float16 qs[64][72];
    __shared__ __align__(16) _Float16 ks[64][72];

    const int wave = tid >> 6, lane = tid & 63;
    const int m16 = lane & 15, quad = lane >> 4;
    const int s0 = stile * 64;
    const int t0 = ttile * 64;
    const int sw = s0 + wave * 16;
    const int diag = (ttile == stile);

    const int srow = tid >> 2;
    const int scol = (tid & 3) * 16;

    const _Float16* qsrc = q_all + ((long)(b * 1024 + s0 + srow)) * 1024 + scol;
    const _Float16* ksrc = k_all + ((long)(b * 1024 + t0 + srow)) * 1024 + scol;
    const long sbase = ((long)(b * 16)) * 1024 + sw + quad * 4;

    float pm[4][4];
#pragma unroll
    for (int c = 0; c < 4; ++c)
#pragma unroll
        for (int r = 0; r < 4; ++r) pm[c][r] = 0.f;

    for (int h = 0; h < 16; ++h) {
        const int ho = h * 64;
        const half8 q0 = *(const half8*)(qsrc + ho);
        const half8 q1 = *(const half8*)(qsrc + ho + 8);
        const half8 k0 = *(const half8*)(ksrc + ho);
        const half8 k1 = *(const half8*)(ksrc + ho + 8);
        const long idx = sbase + (long)h * 1024;
        const float4 mv = *(const float4*)&m_in[idx];
        const float4 iv = *(const float4*)&il_in[idx];

        __syncthreads();
        *(half8*)&qs[srow][scol]     = q0;
        *(half8*)&qs[srow][scol + 8] = q1;
        *(half8*)&ks[srow][scol]     = k0;
        *(half8*)&ks[srow][scol + 8] = k1;
        __syncthreads();

        const half8 a0 = *(const half8*)&qs[wave * 16 + m16][quad * 8];
        const half8 a1 = *(const half8*)&qs[wave * 16 + m16][quad * 8 + 32];
        const float mrow[4] = {mv.x, mv.y, mv.z, mv.w};
        const float irow[4] = {iv.x, iv.y, iv.z, iv.w};

        if (!diag) {
#pragma unroll
            for (int c = 0; c < 4; ++c) {
                const half8 b0 = *(const half8*)&ks[c * 16 + m16][quad * 8];
                const half8 b1 = *(const half8*)&ks[c * 16 + m16][quad * 8 + 32];
                f32x4 cc = {0.f, 0.f, 0.f, 0.f};
                cc = MFMA16(a0, b0, cc);
                cc = MFMA16(a1, b1, cc);
#pragma unroll
                for (int r = 0; r < 4; ++r)
                    pm[c][r] += __expf(cc[r] * 0.125f - mrow[r]) * irow[r];
            }
        } else {
#pragma unroll
            for (int c = 0; c < 4; ++c) {
                const half8 b0 = *(const half8*)&ks[c * 16 + m16][quad * 8];
                const half8 b1 = *(const half8*)&ks[c * 16 + m16][quad * 8 + 32];
                f32x4 cc = {0.f, 0.f, 0.f, 0.f};
                cc = MFMA16(a0, b0, cc);
                cc = MFMA16(a1, b1, cc);
                const int col = t0 + c * 16 + m16;
#pragma unroll
                for (int r = 0; r < 4; ++r) {
                    const int row = sw + quad * 4 + r;
                    if (col <= row)
                        pm[c][r] += __expf(cc[r] * 0.125f - mrow[r]) * irow[r];
                }
            }
        }
    }

#pragma unroll
    for (int c = 0; c < 4; ++c) {
#pragma unroll
        for (int r = 0; r < 4; ++r) {
            const int row = sw + quad * 4 + r;
            const int col = t0 + c * 16 + m16;
            attn[((long)(b * 1024 + row)) * 1024 + col] = pm[c][r] * 0.0625f;
        }
    }
}

// ---------------------------------------------------------------------------
extern "C" void kernel_launch(void* const* d_in, const int* in_sizes, int n_in,
                              void* d_out, int out_size, void* d_ws, size_t ws_size,
                              hipStream_t stream)
{
    const float* queries = (const float*)d_in[0];
    const float* keys    = (const float*)d_in[1];
    const float* values  = (const float*)d_in[2];
    const float* Wq = (const float*)d_in[4];
    const float* bq = (const float*)d_in[5];
    const float* Wk = (const float*)d_in[6];
    const float* bk = (const float*)d_in[7];
    const float* Wv = (const float*)d_in[8];
    const float* bv = (const float*)d_in[9];
    const float* Wo = (const float*)d_in[10];
    const float* bo = (const float*)d_in[11];

    float* out_ptr  = (float*)d_out;                   // [4096][1024]
    float* attn_ptr = out_ptr + (long)4096 * 1024;     // [4][1024][1024]

    uint8_t* w = (uint8_t*)d_ws;
    size_t off = 0;
    auto alloc = [&](size_t bytes) {
        void* p = w + off;
        off = (off + bytes + 255) & ~(size_t)255;
        return p;
    };
    _Float16* WqkT  = (_Float16*)alloc((size_t)2 * 1024 * 1024 * 2); // WqT|WkT [n][d]
    _Float16* WvT   = (_Float16*)alloc((size_t)64 * 1024 * 2);       // [e][d]
    _Float16* WoT   = (_Float16*)alloc((size_t)1024 * 64 * 2);       // [d][e]
    _Float16* qkall = (_Float16*)alloc((size_t)2 * 4194304 * 2);     // qall|kall
    float*    vbuf  = (float*)alloc((size_t)4096 * 64 * 4);
    _Float16* vT    = (_Float16*)alloc((size_t)4 * 64 * 1024 * 2);   // per-b [e][t]
    float*    ctx   = (float*)alloc((size_t)4096 * 64 * 4);
    float*    mbuf  = (float*)alloc((size_t)65536 * 4);
    float*    ilbuf = (float*)alloc((size_t)65536 * 4);
    (void)ws_size; (void)in_sizes; (void)n_in; (void)out_size;

    _Float16* qall = qkall;
    _Float16* kall = qkall + (long)4194304;

    // weight transposes/conversions
    transpose_to_f16<<<dim3(2, 32, 16), 256, 0, stream>>>(Wq, WqkT, 1024, 64, 65536, 65536);
    transpose_to_f16<<<dim3(2, 32, 16), 256, 0, stream>>>(Wk, WqkT + (long)1024 * 1024, 1024, 64, 65536, 65536);
    transpose_to_f16<<<dim3(2, 32, 1),  256, 0, stream>>>(Wv, WvT, 1024, 64, 0, 0);
    transpose_to_f16<<<dim3(32, 2, 1),  256, 0, stream>>>(Wo, WoT, 64, 1024, 0, 0);

    // fused q+k projection: z selects queries/Wq/bq vs keys/Wk/bk; 512 blocks
    gemm_f16_v2<<<dim3(8, 32, 2), 256, 0, stream>>>(
        queries, keys, WqkT, bq, bk, qkall,
        1024, 1024, 1024, 1024,
        0, (long)1048576, (long)4194304,
        /*c_half=*/1, /*atomic=*/0, /*nks=*/1, /*kchunk=*/1024);

    // v projection: split-K x8 atomic into vbuf (zeroed) -> 256 blocks
    hipMemsetAsync(vbuf, 0, (size_t)4096 * 64 * 4, stream);
    gemm_f16_v2<<<dim3(1, 32, 8), 256, 0, stream>>>(
        values, nullptr, WvT, bv, nullptr, vbuf,
        64, 1024, 1024, 64,
        0, 0, 0,
        /*c_half=*/0, /*atomic=*/1, /*nks=*/8, /*kchunk=*/128);

    // vT per batch: [1024][64] -> [64][1024] fp16
    transpose_to_f16<<<dim3(2, 32, 4), 256, 0, stream>>>(vbuf, vT, 1024, 64, 65536, 65536);

    // softmax stats then LDS-staged head-averaged probabilities
    attn_stats<<<dim3(16, 16, 4), 256, 0, stream>>>(qall, kall, mbuf, ilbuf);
    attn_pmean<<<dim3(16, 16, 4), 256, 0, stream>>>(qall, kall, mbuf, ilbuf, attn_ptr);

    // ctx[b] = attn_mean[b] @ v[b]: batch x split-K x8 atomic -> 256 blocks
    hipMemsetAsync(ctx, 0, (size_t)4096 * 64 * 4, stream);
    gemm_f16_v2<<<dim3(1, 8, 32), 256, 0, stream>>>(
        attn_ptr, nullptr, vT, nullptr, nullptr, ctx,
        64, 1024, 1024, 64,
        (long)1048576, (long)65536, (long)65536,
        /*c_half=*/0, /*atomic=*/1, /*nks=*/8, /*kchunk=*/128);

    // out = ctx @ Wo + bo (K=64: single iteration)
    gemm_f16_v2<<<dim3(8, 32, 1), 256, 0, stream>>>(
        ctx, nullptr, WoT, bo, nullptr, out_ptr,
        1024, 64, 64, 1024,
        0, 0, 0,
        /*c_half=*/0, /*atomic=*/0, /*nks=*/1, /*kchunk=*/64);
}

// Round 3
// 252.922 us; speedup vs baseline: 1.0161x; 1.0161x over previous
//
#include <hip/hip_runtime.h>
#include <hip/hip_bf16.h>
#include <stdint.h>

typedef _Float16 half8 __attribute__((ext_vector_type(8)));
typedef _Float16 half4 __attribute__((ext_vector_type(4)));
typedef float    f32x4 __attribute__((ext_vector_type(4)));

#define MFMA16(a, b, c) __builtin_amdgcn_mfma_f32_16x16x32_f16(a, b, c, 0, 0, 0)

// global_load_lds helper: 16B per lane, LDS dest = wave-uniform base + lane*16.
typedef __attribute__((address_space(1))) const void GVOID;
typedef __attribute__((address_space(3))) void LVOID;
__device__ __forceinline__ void glds16(const void* g, void* l)
{
    __builtin_amdgcn_global_load_lds((GVOID*)g, (LVOID*)l, 16, 0, 0);
}

// ---------------------------------------------------------------------------
// Generic fp32->fp16 transpose: X [R][C] fp32 -> Y [C][R] fp16, z-batched.
// ---------------------------------------------------------------------------
__global__ __launch_bounds__(256) void transpose_to_f16(
    const float* __restrict__ X, _Float16* __restrict__ Y,
    int R, int C, long inBS, long outBS)
{
    __shared__ float t[32][33];
    const int bz = blockIdx.z;
    X += (long)bz * inBS;
    Y += (long)bz * outBS;
    const int c0 = blockIdx.x * 32, r0 = blockIdx.y * 32;
    const int tx = threadIdx.x & 31, ty = threadIdx.x >> 5;
#pragma unroll
    for (int i = 0; i < 4; ++i)
        t[ty + i * 8][tx] = X[(long)(r0 + ty + i * 8) * C + c0 + tx];
    __syncthreads();
#pragma unroll
    for (int i = 0; i < 4; ++i)
        Y[(long)(c0 + ty + i * 8) * R + r0 + tx] = (_Float16)t[tx][ty + i * 8];
}

// ---------------------------------------------------------------------------
// fp32 -> fp16 convert for q/k activations: D[z] = (fp16)Sz, 4194304 elems each.
// ---------------------------------------------------------------------------
__global__ __launch_bounds__(256) void cvt_qk_f16(
    const float* __restrict__ S0, const float* __restrict__ S1,
    _Float16* __restrict__ D)
{
    const float* S = blockIdx.y ? S1 : S0;
    _Float16* Dz = D + (long)blockIdx.y * 4194304;
    const long i = ((long)blockIdx.x * 256 + threadIdx.x) * 8;
    const float4 v0 = *(const float4*)(S + i);
    const float4 v1 = *(const float4*)(S + i + 4);
    half8 h;
    h[0] = (_Float16)v0.x; h[1] = (_Float16)v0.y;
    h[2] = (_Float16)v0.z; h[3] = (_Float16)v0.w;
    h[4] = (_Float16)v1.x; h[5] = (_Float16)v1.y;
    h[6] = (_Float16)v1.z; h[7] = (_Float16)v1.w;
    *(half8*)(Dz + i) = h;
}

// ---------------------------------------------------------------------------
// q+k projection GEMM v5: glds + XOR-swizzled linear LDS + double-buffer,
// one barrier per K-step (T3 minimum 2-phase template).
// R1/R2 post-mortem: reg-staged prefetch is unpinnable (VGPR stayed 76 across
// both attempts -> loads sunk to use site, full latency exposed every step).
// global_load_lds has NO VGPR destination -> nothing to sink; prefetch of
// tile t+1 is issued before tile t's MFMA phase and its vmcnt drains at the
// closing __syncthreads -- exactly where buffer cur^1 must be complete.
// LDS layout: [128][64] fp16 unpadded (glds needs linear rows); 16-way read
// conflict fixed by XOR swizzle applied BOTH on global source address and on
// fragment-read address (rule #21): colbyte ^= (row&7)<<4.
// A is fp16 (pre-converted) -> A staging traffic halved vs fp32.
// ---------------------------------------------------------------------------
__global__ __launch_bounds__(256, 2) void gemm_qk_glds(
    const _Float16* __restrict__ A16,   // [2][4096][1024] fp16 (q16|k16)
    const _Float16* __restrict__ BT,    // [2][1024][1024] fp16 (WqT|WkT)
    const float* __restrict__ bias0, const float* __restrict__ bias1,
    _Float16* __restrict__ Cout)        // [2][4096][1024] fp16 (qall|kall)
{
    __shared__ __align__(16) _Float16 As[2][128 * 64];
    __shared__ __align__(16) _Float16 Bs[2][128 * 64];

    // XCD-aware bijective swizzle (nwg = 512, divisible by 8)
    const int gx  = gridDim.x, gy = gridDim.y;
    const int nwg = gx * gy * (int)gridDim.z;
    const int lid = (int)blockIdx.x + gx * ((int)blockIdx.y + gy * (int)blockIdx.z);
    const int q8  = nwg >> 3;
    const int xcd = lid & 7, loc = lid >> 3;
    const int sw  = xcd * q8 + loc;
    const int nt  = sw % gx;
    const int tm2 = sw / gx;
    const int mt  = tm2 % gy;
    const int z   = tm2 / gy;           // 0 = q, 1 = k

    const int n0 = nt * 128;
    const int m0 = mt * 128;
    const int tid  = threadIdx.x;
    const int wave = tid >> 6, lane = tid & 63;
    const int m16  = lane & 15, quad = lane >> 4;

    const char* Az = (const char*)(A16 + (long)z * 4194304);
    const char* Bz = (const char*)(BT  + (long)z * 1048576);

    // per-lane glds source base: row = wave*32 + (lane>>3) (+i*8), 2048 B/row;
    // swizzled col chunk = ((lane&7) ^ (lane>>3)) * 16 bytes.
    const int colbyte = (((lane & 7) ^ (lane >> 3)) << 4);
    const char* gaBase = Az + ((long)(m0 + wave * 32 + (lane >> 3)) << 11) + colbyte;
    const char* gbBase = Bz + ((long)(n0 + wave * 32 + (lane >> 3)) << 11) + colbyte;

    f32x4 acc[2][8];
    {
        f32x4 zz = {0.f, 0.f, 0.f, 0.f};
#pragma unroll
        for (int i = 0; i < 2; ++i)
#pragma unroll
            for (int j = 0; j < 8; ++j) acc[i][j] = zz;
    }

    auto STAGE = [&](int bf, int k0) {
        const char* ga = gaBase + (k0 << 1);
        const char* gb = gbBase + (k0 << 1);
        _Float16* la = &As[bf][wave * 32 * 64];
        _Float16* lb = &Bs[bf][wave * 32 * 64];
#pragma unroll
        for (int i = 0; i < 4; ++i) {
            glds16(ga + (long)i * 8 * 2048, la + i * 8 * 64);
            glds16(gb + (long)i * 8 * 2048, lb + i * 8 * 64);
        }
    };

    auto COMPUTE = [&](int bf) {
        const char* Ab = (const char*)&As[bf][0];
        const char* Bp = (const char*)&Bs[bf][0];
        const int sw4 = (m16 & 7) << 4;
#pragma unroll
        for (int kss = 0; kss < 2; ++kss) {
            const int kbs = (kss * 64 + quad * 16) ^ sw4;
            const half8 a0 = *(const half8*)(Ab + (wave * 32 + m16) * 128 + kbs);
            const half8 a1 = *(const half8*)(Ab + (wave * 32 + 16 + m16) * 128 + kbs);
#pragma unroll
            for (int c = 0; c < 8; ++c) {
                const half8 bfr = *(const half8*)(Bp + (c * 16 + m16) * 128 + kbs);
                acc[0][c] = MFMA16(a0, bfr, acc[0][c]);
                acc[1][c] = MFMA16(a1, bfr, acc[1][c]);
            }
        }
    };

    STAGE(0, 0);
    __syncthreads();                   // vmcnt(0) drain: buf0 complete
    int cur = 0;
    for (int k0 = 0; k0 < 1024; k0 += 64) {
        if (k0 + 64 < 1024) STAGE(cur ^ 1, k0 + 64);  // DMA issue, no VGPR dest
        COMPUTE(cur);                                  // latency hides here
        __syncthreads();               // drains this step's glds; buf swap safe
        cur ^= 1;
    }

    const float* bias = z ? bias1 : bias0;
    _Float16* Cz = Cout + (long)z * 4194304;
#pragma unroll
    for (int hh = 0; hh < 2; ++hh) {
#pragma unroll
        for (int c = 0; c < 8; ++c) {
            const int col = n0 + c * 16 + m16;
            const float bb = bias[col];
#pragma unroll
            for (int r = 0; r < 4; ++r) {
                const int row = m0 + wave * 32 + hh * 16 + quad * 4 + r;
                Cz[(long)row * 1024 + col] = (_Float16)(acc[hh][c][r] + bb);
            }
        }
    }
}

// ---------------------------------------------------------------------------
// MFMA GEMM (fp32 A path) — used for v-proj / ctx / out. R1 body with the
// regressive sched_barrier removed.
// ---------------------------------------------------------------------------
__global__ __launch_bounds__(256, 2) void gemm_f16_v2(
    const float* __restrict__ A0, const float* __restrict__ A1,
    const _Float16* __restrict__ BT,
    const float* __restrict__ bias0, const float* __restrict__ bias1,
    void* __restrict__ Cout,
    int N, int lda, int ldbt, int ldc,
    long aBS, long bBS, long cBS,
    int c_half, int atomic, int nks, int kchunk)
{
    __shared__ __align__(16) _Float16 As[128][72];
    __shared__ __align__(16) _Float16 Bs[128][72];

    const int gx  = gridDim.x, gy = gridDim.y;
    const int nwg = gx * gy * (int)gridDim.z;
    const int lid = (int)blockIdx.x + gx * ((int)blockIdx.y + gy * (int)blockIdx.z);
    const int q8  = nwg >> 3, r8 = nwg & 7;
    const int xcd = lid & 7, loc = lid >> 3;
    const int sw  = (xcd < r8 ? xcd * (q8 + 1) : r8 * (q8 + 1) + (xcd - r8) * q8) + loc;
    const int nt  = sw % gx;
    const int tm2 = sw / gx;
    const int mt  = tm2 % gy;
    const int bz  = tm2 / gy;

    const int b = bz / nks, ks = bz % nks;
    const int kbeg = ks * kchunk;
    const int kend = kbeg + kchunk;

    const float* A = A1 ? (b ? A1 : A0) : (A0 + (long)b * aBS);
    const _Float16* Bb = BT + (long)b * bBS;

    const int n0 = nt * 128;
    const int m0 = mt * 128;
    const int tid  = threadIdx.x;
    const int wave = tid >> 6, lane = tid & 63;
    const int m16  = lane & 15, quad = lane >> 4;

    const int acol = (tid & 15) * 4;
    const int arb  = tid >> 4;
    const int bj   = tid >> 1;
    const int bcc  = (tid & 1) * 32;
    int jn = n0 + bj; if (jn > N - 1) jn = N - 1;
    const _Float16* bpB = Bb + (long)jn * ldbt;

    f32x4 acc[2][8];
    {
        f32x4 zz = {0.f, 0.f, 0.f, 0.f};
#pragma unroll
        for (int i = 0; i < 2; ++i)
#pragma unroll
            for (int j = 0; j < 8; ++j) acc[i][j] = zz;
    }

    for (int k0 = kbeg; k0 < kend; k0 += 64) {
        {
            const int cc = acol;
            float4 av[8];
#pragma unroll
            for (int p = 0; p < 8; ++p)
                av[p] = *(const float4*)(A + (long)(m0 + arb + p * 16) * lda + k0 + cc);
#pragma unroll
            for (int p = 0; p < 8; ++p) {
                half4 hv;
                hv[0] = (_Float16)av[p].x; hv[1] = (_Float16)av[p].y;
                hv[2] = (_Float16)av[p].z; hv[3] = (_Float16)av[p].w;
                *(half4*)&As[arb + p * 16][cc] = hv;
            }
        }
        {
            const _Float16* bp = bpB + k0 + bcc;
            half8 b0 = *(const half8*)(bp);
            half8 b1 = *(const half8*)(bp + 8);
            half8 b2 = *(const half8*)(bp + 16);
            half8 b3 = *(const half8*)(bp + 24);
            *(half8*)&Bs[bj][bcc]      = b0;
            *(half8*)&Bs[bj][bcc + 8]  = b1;
            *(half8*)&Bs[bj][bcc + 16] = b2;
            *(half8*)&Bs[bj][bcc + 24] = b3;
        }
        __syncthreads();
#pragma unroll
        for (int kss = 0; kss < 2; ++kss) {
            const int ko = kss * 32 + quad * 8;
            const half8 a0 = *(const half8*)&As[wave * 32 + m16][ko];
            const half8 a1 = *(const half8*)&As[wave * 32 + 16 + m16][ko];
#pragma unroll
            for (int c = 0; c < 8; ++c) {
                const half8 bf = *(const half8*)&Bs[c * 16 + m16][ko];
                acc[0][c] = MFMA16(a0, bf, acc[0][c]);
                acc[1][c] = MFMA16(a1, bf, acc[1][c]);
            }
        }
        __syncthreads();
    }

    const float* bias = b ? bias1 : bias0;
    const int addb = (bias != nullptr) && (kbeg == 0);
#pragma unroll
    for (int hh = 0; hh < 2; ++hh) {
#pragma unroll
        for (int c = 0; c < 8; ++c) {
            const int col = n0 + c * 16 + m16;
            if (col >= N) continue;
            const float bb = addb ? bias[col] : 0.f;
#pragma unroll
            for (int r = 0; r < 4; ++r) {
                const int row = m0 + wave * 32 + hh * 16 + quad * 4 + r;
                const float v = acc[hh][c][r] + bb;
                const long idx = (long)b * cBS + (long)row * ldc + col;
                if (atomic)      atomicAdd(&((float*)Cout)[idx], v);
                else if (c_half) ((_Float16*)Cout)[idx] = (_Float16)v;
                else             ((float*)Cout)[idx] = v;
            }
        }
    }
}

// ---------------------------------------------------------------------------
// Pass 1: per (b,h,s) row stats — LDS-staged (unchanged).
// ---------------------------------------------------------------------------
__global__ __launch_bounds__(256, 2) void attn_stats(
    const _Float16* __restrict__ q_all, const _Float16* __restrict__ k_all,
    float* __restrict__ m_out, float* __restrict__ il_out)
{
    const int st = blockIdx.x, h = blockIdx.y, b = blockIdx.z;
    const int tid = threadIdx.x, wave = tid >> 6, lane = tid & 63;
    const int m16 = lane & 15, quad = lane >> 4;
    const int s0 = st * 64;
    const int sw = s0 + wave * 16;

    __shared__ __align__(16) _Float16 qs[64][72];
    __shared__ __align__(16) _Float16 ks[64][72];

    const int srow = tid >> 2;
    const int scol = (tid & 3) * 16;

    {
        const _Float16* qsrc = q_all + ((long)(b * 1024 + s0 + srow)) * 1024 + h * 64 + scol;
        *(half8*)&qs[srow][scol]     = *(const half8*)(qsrc);
        *(half8*)&qs[srow][scol + 8] = *(const half8*)(qsrc + 8);
    }

    const _Float16* ksrcb = k_all + ((long)(b * 1024 + srow)) * 1024 + h * 64 + scol;

    float mr[4], lr[4];
#pragma unroll
    for (int r = 0; r < 4; ++r) { mr[r] = -3.0e38f; lr[r] = 0.f; }

    half8 a0, a1;
    for (int tt = 0; tt <= st; ++tt) {
        const _Float16* ksrc = ksrcb + (long)(tt * 64) * 1024;
        const half8 k0 = *(const half8*)(ksrc);
        const half8 k1 = *(const half8*)(ksrc + 8);

        __syncthreads();
        *(half8*)&ks[srow][scol]     = k0;
        *(half8*)&ks[srow][scol + 8] = k1;
        __syncthreads();

        if (tt == 0) {
            a0 = *(const half8*)&qs[wave * 16 + m16][quad * 8];
            a1 = *(const half8*)&qs[wave * 16 + m16][quad * 8 + 32];
        }

        if (tt < st) {
#pragma unroll
            for (int c = 0; c < 4; ++c) {
                const half8 b0 = *(const half8*)&ks[c * 16 + m16][quad * 8];
                const half8 b1 = *(const half8*)&ks[c * 16 + m16][quad * 8 + 32];
                f32x4 cc = {0.f, 0.f, 0.f, 0.f};
                cc = MFMA16(a0, b0, cc);
                cc = MFMA16(a1, b1, cc);
#pragma unroll
                for (int r = 0; r < 4; ++r) {
                    const float zz = cc[r] * 0.125f;
                    const float nm = fmaxf(mr[r], zz);
                    lr[r] = lr[r] * __expf(mr[r] - nm) + __expf(zz - nm);
                    mr[r] = nm;
                }
            }
        } else {
#pragma unroll
            for (int c = 0; c < 4; ++c) {
                const half8 b0 = *(const half8*)&ks[c * 16 + m16][quad * 8];
                const half8 b1 = *(const half8*)&ks[c * 16 + m16][quad * 8 + 32];
                f32x4 cc = {0.f, 0.f, 0.f, 0.f};
                cc = MFMA16(a0, b0, cc);
                cc = MFMA16(a1, b1, cc);
                const int col = tt * 64 + c * 16 + m16;
#pragma unroll
                for (int r = 0; r < 4; ++r) {
                    const int row = sw + quad * 4 + r;
                    if (col <= row) {
                        const float zz = cc[r] * 0.125f;
                        const float nm = fmaxf(mr[r], zz);
                        lr[r] = lr[r] * __expf(mr[r] - nm) + __expf(zz - nm);
                        mr[r] = nm;
                    }
                }
            }
        }
    }

#pragma unroll
    for (int mk = 1; mk < 16; mk <<= 1) {
#pragma unroll
        for (int r = 0; r < 4; ++r) {
            const float om = __shfl_xor(mr[r], mk);
            const float ol = __shfl_xor(lr[r], mk);
            const float nm = fmaxf(mr[r], om);
            lr[r] = lr[r] * __expf(mr[r] - nm) + ol * __expf(om - nm);
            mr[r] = nm;
        }
    }
    if (m16 == 0) {
#pragma unroll
        for (int r = 0; r < 4; ++r) {
            const long idx = ((long)(b * 16 + h)) * 1024 + sw + quad * 4 + r;
            m_out[idx]  = mr[r];
            il_out[idx] = 1.f / lr[r];
        }
    }
}

// ---------------------------------------------------------------------------
// Pass 2: attn_mean = (1/H) sum_h softmax — LDS-staged (unchanged).
// ---------------------------------------------------------------------------
__global__ __launch_bounds__(256, 2) void attn_pmean(
    const _Float16* __restrict__ q_all, const _Float16* __restrict__ k_all,
    const float* __restrict__ m_in, const float* __restrict__ il_in,
    float* __restrict__ attn)
{
    const int ttile = blockIdx.x, stile = blockIdx.y, b = blockIdx.z;
    const int tid = threadIdx.x;
    if (ttile > stile) {
        const int c4 = (tid & 15) * 4;
        float4 zz = {0.f, 0.f, 0.f, 0.f};
#pragma unroll
        for (int i = 0; i < 4; ++i) {
            const int r = stile * 64 + (tid >> 4) + i * 16;
            *(float4*)&attn[((long)(b * 1024 + r)) * 1024 + ttile * 64 + c4] = zz;
        }
        return;
    }

    __shared__ __align__(16) _Float16 qs[64][72];
    __shared__ __align__(16) _Float16 ks[64][72];

    const int wave = tid >> 6, lane = tid & 63;
    const int m16 = lane & 15, quad = lane >> 4;
    const int s0 = stile * 64;
    const int t0 = ttile * 64;
    const int sw = s0 + wave * 16;
    const int diag = (ttile == stile);

    const int srow = tid >> 2;
    const int scol = (tid & 3) * 16;

    const _Float16* qsrc = q_all + ((long)(b * 1024 + s0 + srow)) * 1024 + scol;
    const _Float16* ksrc = k_all + ((long)(b * 1024 + t0 + srow)) * 1024 + scol;
    const long sbase = ((long)(b * 16)) * 1024 + sw + quad * 4;

    float pm[4][4];
#pragma unroll
    for (int c = 0; c < 4; ++c)
#pragma unroll
        for (int r = 0; r < 4; ++r) pm[c][r] = 0.f;

    for (int h = 0; h < 16; ++h) {
        const int ho = h * 64;
        const half8 q0 = *(const half8*)(qsrc + ho);
        const half8 q1 = *(const half8*)(qsrc + ho + 8);
        const half8 k0 = *(const half8*)(ksrc + ho);
        const half8 k1 = *(const half8*)(ksrc + ho + 8);
        const long idx = sbase + (long)h * 1024;
        const float4 mv = *(const float4*)&m_in[idx];
        const float4 iv = *(const float4*)&il_in[idx];

        __syncthreads();
        *(half8*)&qs[srow][scol]     = q0;
        *(half8*)&qs[srow][scol + 8] = q1;
        *(half8*)&ks[srow][scol]     = k0;
        *(half8*)&ks[srow][scol + 8] = k1;
        __syncthreads();

        const half8 a0 = *(const half8*)&qs[wave * 16 + m16][quad * 8];
        const half8 a1 = *(const half8*)&qs[wave * 16 + m16][quad * 8 + 32];
        const float mrow[4] = {mv.x, mv.y, mv.z, mv.w};
        const float irow[4] = {iv.x, iv.y, iv.z, iv.w};

        if (!diag) {
#pragma unroll
            for (int c = 0; c < 4; ++c) {
                const half8 b0 = *(const half8*)&ks[c * 16 + m16][quad * 8];
                const half8 b1 = *(const half8*)&ks[c * 16 + m16][quad * 8 + 32];
                f32x4 cc = {0.f, 0.f, 0.f, 0.f};
                cc = MFMA16(a0, b0, cc);
                cc = MFMA16(a1, b1, cc);
#pragma unroll
                for (int r = 0; r < 4; ++r)
                    pm[c][r] += __expf(cc[r] * 0.125f - mrow[r]) * irow[r];
            }
        } else {
#pragma unroll
            for (int c = 0; c < 4; ++c) {
                const half8 b0 = *(const half8*)&ks[c * 16 + m16][quad * 8];
                const half8 b1 = *(const half8*)&ks[c * 16 + m16][quad * 8 + 32];
                f32x4 cc = {0.f, 0.f, 0.f, 0.f};
                cc = MFMA16(a0, b0, cc);
                cc = MFMA16(a1, b1, cc);
                const int col = t0 + c * 16 + m16;
#pragma unroll
                for (int r = 0; r < 4; ++r) {
                    const int row = sw + quad * 4 + r;
                    if (col <= row)
                        pm[c][r] += __expf(cc[r] * 0.125f - mrow[r]) * irow[r];
                }
            }
        }
    }

#pragma unroll
    for (int c = 0; c < 4; ++c) {
#pragma unroll
        for (int r = 0; r < 4; ++r) {
            const int row = sw + quad * 4 + r;
            const int col = t0 + c * 16 + m16;
            attn[((long)(b * 1024 + row)) * 1024 + col] = pm[c][r] * 0.0625f;
        }
    }
}

// ---------------------------------------------------------------------------
extern "C" void kernel_launch(void* const* d_in, const int* in_sizes, int n_in,
                              void* d_out, int out_size, void* d_ws, size_t ws_size,
                              hipStream_t stream)
{
    const float* queries = (const float*)d_in[0];
    const float* keys    = (const float*)d_in[1];
    const float* values  = (const float*)d_in[2];
    const float* Wq = (const float*)d_in[4];
    const float* bq = (const float*)d_in[5];
    const float* Wk = (const float*)d_in[6];
    const float* bk = (const float*)d_in[7];
    const float* Wv = (const float*)d_in[8];
    const float* bv = (const float*)d_in[9];
    const float* Wo = (const float*)d_in[10];
    const float* bo = (const float*)d_in[11];

    float* out_ptr  = (float*)d_out;                   // [4096][1024]
    float* attn_ptr = out_ptr + (long)4096 * 1024;     // [4][1024][1024]

    uint8_t* w = (uint8_t*)d_ws;
    size_t off = 0;
    auto alloc = [&](size_t bytes) {
        void* p = w + off;
        off = (off + bytes + 255) & ~(size_t)255;
        return p;
    };
    _Float16* WqkT  = (_Float16*)alloc((size_t)2 * 1024 * 1024 * 2); // WqT|WkT [n][d]
    _Float16* WvT   = (_Float16*)alloc((size_t)64 * 1024 * 2);       // [e][d]
    _Float16* WoT   = (_Float16*)alloc((size_t)1024 * 64 * 2);       // [d][e]
    _Float16* qkall = (_Float16*)alloc((size_t)2 * 4194304 * 2);     // qall|kall
    _Float16* a16   = (_Float16*)alloc((size_t)2 * 4194304 * 2);     // q16|k16 inputs
    float*    vbuf  = (float*)alloc((size_t)4096 * 64 * 4);
    _Float16* vT    = (_Float16*)alloc((size_t)4 * 64 * 1024 * 2);   // per-b [e][t]
    float*    ctx   = (float*)alloc((size_t)4096 * 64 * 4);
    float*    mbuf  = (float*)alloc((size_t)65536 * 4);
    float*    ilbuf = (float*)alloc((size_t)65536 * 4);
    (void)ws_size; (void)in_sizes; (void)n_in; (void)out_size;

    _Float16* qall = qkall;
    _Float16* kall = qkall + (long)4194304;

    // weight transposes/conversions + activation fp16 convert
    transpose_to_f16<<<dim3(2, 32, 16), 256, 0, stream>>>(Wq, WqkT, 1024, 64, 65536, 65536);
    transpose_to_f16<<<dim3(2, 32, 16), 256, 0, stream>>>(Wk, WqkT + (long)1024 * 1024, 1024, 64, 65536, 65536);
    transpose_to_f16<<<dim3(2, 32, 1),  256, 0, stream>>>(Wv, WvT, 1024, 64, 0, 0);
    transpose_to_f16<<<dim3(32, 2, 1),  256, 0, stream>>>(Wo, WoT, 64, 1024, 0, 0);
    cvt_qk_f16<<<dim3(2048, 2, 1), 256, 0, stream>>>(queries, keys, a16);

    // fused q+k projection: glds 2-phase double-buffered kernel
    gemm_qk_glds<<<dim3(8, 32, 2), 256, 0, stream>>>(
        a16, WqkT, bq, bk, qkall);

    // v projection: split-K x8 atomic into vbuf (zeroed) -> 256 blocks
    hipMemsetAsync(vbuf, 0, (size_t)4096 * 64 * 4, stream);
    gemm_f16_v2<<<dim3(1, 32, 8), 256, 0, stream>>>(
        values, nullptr, WvT, bv, nullptr, vbuf,
        64, 1024, 1024, 64,
        0, 0, 0,
        /*c_half=*/0, /*atomic=*/1, /*nks=*/8, /*kchunk=*/128);

    // vT per batch: [1024][64] -> [64][1024] fp16
    transpose_to_f16<<<dim3(2, 32, 4), 256, 0, stream>>>(vbuf, vT, 1024, 64, 65536, 65536);

    // softmax stats then LDS-staged head-averaged probabilities
    attn_stats<<<dim3(16, 16, 4), 256, 0, stream>>>(qall, kall, mbuf, ilbuf);
    attn_pmean<<<dim3(16, 16, 4), 256, 0, stream>>>(qall, kall, mbuf, ilbuf, attn_ptr);

    // ctx[b] = attn_mean[b] @ v[b]: batch x split-K x8 atomic -> 256 blocks
    hipMemsetAsync(ctx, 0, (size_t)4096 * 64 * 4, stream);
    gemm_f16_v2<<<dim3(1, 8, 32), 256, 0, stream>>>(
        attn_ptr, nullptr, vT, nullptr, nullptr, ctx,
        64, 1024, 1024, 64,
        (long)1048576, (long)65536, (long)65536,
        /*c_half=*/0, /*atomic=*/1, /*nks=*/8, /*kchunk=*/128);

    // out = ctx @ Wo + bo (K=64: single iteration)
    gemm_f16_v2<<<dim3(8, 32, 1), 256, 0, stream>>>(
        ctx, nullptr, WoT, bo, nullptr, out_ptr,
        1024, 64, 64, 1024,
        0, 0, 0,
        /*c_half=*/0, /*atomic=*/0, /*nks=*/1, /*kchunk=*/64);
}

// Round 4
// 241.806 us; speedup vs baseline: 1.0628x; 1.0460x over previous
//
#include <hip/hip_runtime.h>
#include <hip/hip_bf16.h>
#include <stdint.h>

typedef _Float16 half8 __attribute__((ext_vector_type(8)));
typedef _Float16 half4 __attribute__((ext_vector_type(4)));
typedef float    f32x4 __attribute__((ext_vector_type(4)));

#define MFMA16(a, b, c) __builtin_amdgcn_mfma_f32_16x16x32_f16(a, b, c, 0, 0, 0)

// global_load_lds helper: 16B per lane, LDS dest = wave-uniform base + lane*16.
typedef __attribute__((address_space(1))) const void GVOID;
typedef __attribute__((address_space(3))) void LVOID;
__device__ __forceinline__ void glds16(const void* g, void* l)
{
    __builtin_amdgcn_global_load_lds((GVOID*)g, (LVOID*)l, 16, 0, 0);
}

// ---------------------------------------------------------------------------
// Generic fp32->fp16 transpose: X [R][C] fp32 -> Y [C][R] fp16, z-batched.
// ---------------------------------------------------------------------------
__global__ __launch_bounds__(256) void transpose_to_f16(
    const float* __restrict__ X, _Float16* __restrict__ Y,
    int R, int C, long inBS, long outBS)
{
    __shared__ float t[32][33];
    const int bz = blockIdx.z;
    X += (long)bz * inBS;
    Y += (long)bz * outBS;
    const int c0 = blockIdx.x * 32, r0 = blockIdx.y * 32;
    const int tx = threadIdx.x & 31, ty = threadIdx.x >> 5;
#pragma unroll
    for (int i = 0; i < 4; ++i)
        t[ty + i * 8][tx] = X[(long)(r0 + ty + i * 8) * C + c0 + tx];
    __syncthreads();
#pragma unroll
    for (int i = 0; i < 4; ++i)
        Y[(long)(c0 + ty + i * 8) * R + r0 + tx] = (_Float16)t[tx][ty + i * 8];
}

// ---------------------------------------------------------------------------
// fp32 -> fp16 convert for q/k activations: D[z] = (fp16)Sz, 4194304 elems each.
// ---------------------------------------------------------------------------
__global__ __launch_bounds__(256) void cvt_qk_f16(
    const float* __restrict__ S0, const float* __restrict__ S1,
    _Float16* __restrict__ D)
{
    const float* S = blockIdx.y ? S1 : S0;
    _Float16* Dz = D + (long)blockIdx.y * 4194304;
    const long i = ((long)blockIdx.x * 256 + threadIdx.x) * 8;
    const float4 v0 = *(const float4*)(S + i);
    const float4 v1 = *(const float4*)(S + i + 4);
    half8 h;
    h[0] = (_Float16)v0.x; h[1] = (_Float16)v0.y;
    h[2] = (_Float16)v0.z; h[3] = (_Float16)v0.w;
    h[4] = (_Float16)v1.x; h[5] = (_Float16)v1.y;
    h[6] = (_Float16)v1.z; h[7] = (_Float16)v1.w;
    *(half8*)(Dz + i) = h;
}

// ---------------------------------------------------------------------------
// q+k projection GEMM: glds + XOR-swizzled linear LDS + double-buffer,
// one barrier per K-step (unchanged from R3-passing).
// ---------------------------------------------------------------------------
__global__ __launch_bounds__(256, 2) void gemm_qk_glds(
    const _Float16* __restrict__ A16,   // [2][4096][1024] fp16 (q16|k16)
    const _Float16* __restrict__ BT,    // [2][1024][1024] fp16 (WqT|WkT)
    const float* __restrict__ bias0, const float* __restrict__ bias1,
    _Float16* __restrict__ Cout)        // [2][4096][1024] fp16 (qall|kall)
{
    __shared__ __align__(16) _Float16 As[2][128 * 64];
    __shared__ __align__(16) _Float16 Bs[2][128 * 64];

    const int gx  = gridDim.x, gy = gridDim.y;
    const int nwg = gx * gy * (int)gridDim.z;
    const int lid = (int)blockIdx.x + gx * ((int)blockIdx.y + gy * (int)blockIdx.z);
    const int q8  = nwg >> 3;
    const int xcd = lid & 7, loc = lid >> 3;
    const int sw  = xcd * q8 + loc;
    const int nt  = sw % gx;
    const int tm2 = sw / gx;
    const int mt  = tm2 % gy;
    const int z   = tm2 / gy;           // 0 = q, 1 = k

    const int n0 = nt * 128;
    const int m0 = mt * 128;
    const int tid  = threadIdx.x;
    const int wave = tid >> 6, lane = tid & 63;
    const int m16  = lane & 15, quad = lane >> 4;

    const char* Az = (const char*)(A16 + (long)z * 4194304);
    const char* Bz = (const char*)(BT  + (long)z * 1048576);

    const int colbyte = (((lane & 7) ^ (lane >> 3)) << 4);
    const char* gaBase = Az + ((long)(m0 + wave * 32 + (lane >> 3)) << 11) + colbyte;
    const char* gbBase = Bz + ((long)(n0 + wave * 32 + (lane >> 3)) << 11) + colbyte;

    f32x4 acc[2][8];
    {
        f32x4 zz = {0.f, 0.f, 0.f, 0.f};
#pragma unroll
        for (int i = 0; i < 2; ++i)
#pragma unroll
            for (int j = 0; j < 8; ++j) acc[i][j] = zz;
    }

    auto STAGE = [&](int bf, int k0) {
        const char* ga = gaBase + (k0 << 1);
        const char* gb = gbBase + (k0 << 1);
        _Float16* la = &As[bf][wave * 32 * 64];
        _Float16* lb = &Bs[bf][wave * 32 * 64];
#pragma unroll
        for (int i = 0; i < 4; ++i) {
            glds16(ga + (long)i * 8 * 2048, la + i * 8 * 64);
            glds16(gb + (long)i * 8 * 2048, lb + i * 8 * 64);
        }
    };

    auto COMPUTE = [&](int bf) {
        const char* Ab = (const char*)&As[bf][0];
        const char* Bp = (const char*)&Bs[bf][0];
        const int sw4 = (m16 & 7) << 4;
#pragma unroll
        for (int kss = 0; kss < 2; ++kss) {
            const int kbs = (kss * 64 + quad * 16) ^ sw4;
            const half8 a0 = *(const half8*)(Ab + (wave * 32 + m16) * 128 + kbs);
            const half8 a1 = *(const half8*)(Ab + (wave * 32 + 16 + m16) * 128 + kbs);
#pragma unroll
            for (int c = 0; c < 8; ++c) {
                const half8 bfr = *(const half8*)(Bp + (c * 16 + m16) * 128 + kbs);
                acc[0][c] = MFMA16(a0, bfr, acc[0][c]);
                acc[1][c] = MFMA16(a1, bfr, acc[1][c]);
            }
        }
    };

    STAGE(0, 0);
    __syncthreads();
    int cur = 0;
    for (int k0 = 0; k0 < 1024; k0 += 64) {
        if (k0 + 64 < 1024) STAGE(cur ^ 1, k0 + 64);
        COMPUTE(cur);
        __syncthreads();
        cur ^= 1;
    }

    const float* bias = z ? bias1 : bias0;
    _Float16* Cz = Cout + (long)z * 4194304;
#pragma unroll
    for (int hh = 0; hh < 2; ++hh) {
#pragma unroll
        for (int c = 0; c < 8; ++c) {
            const int col = n0 + c * 16 + m16;
            const float bb = bias[col];
#pragma unroll
            for (int r = 0; r < 4; ++r) {
                const int row = m0 + wave * 32 + hh * 16 + quad * 4 + r;
                Cz[(long)row * 1024 + col] = (_Float16)(acc[hh][c][r] + bb);
            }
        }
    }
}

// ---------------------------------------------------------------------------
// MFMA GEMM (fp32 A path) — used for v-proj / out (ctx GEMM is now fused
// into attn_pmean).
// ---------------------------------------------------------------------------
__global__ __launch_bounds__(256, 2) void gemm_f16_v2(
    const float* __restrict__ A0, const float* __restrict__ A1,
    const _Float16* __restrict__ BT,
    const float* __restrict__ bias0, const float* __restrict__ bias1,
    void* __restrict__ Cout,
    int N, int lda, int ldbt, int ldc,
    long aBS, long bBS, long cBS,
    int c_half, int atomic, int nks, int kchunk)
{
    __shared__ __align__(16) _Float16 As[128][72];
    __shared__ __align__(16) _Float16 Bs[128][72];

    const int gx  = gridDim.x, gy = gridDim.y;
    const int nwg = gx * gy * (int)gridDim.z;
    const int lid = (int)blockIdx.x + gx * ((int)blockIdx.y + gy * (int)blockIdx.z);
    const int q8  = nwg >> 3, r8 = nwg & 7;
    const int xcd = lid & 7, loc = lid >> 3;
    const int sw  = (xcd < r8 ? xcd * (q8 + 1) : r8 * (q8 + 1) + (xcd - r8) * q8) + loc;
    const int nt  = sw % gx;
    const int tm2 = sw / gx;
    const int mt  = tm2 % gy;
    const int bz  = tm2 / gy;

    const int b = bz / nks, ks = bz % nks;
    const int kbeg = ks * kchunk;
    const int kend = kbeg + kchunk;

    const float* A = A1 ? (b ? A1 : A0) : (A0 + (long)b * aBS);
    const _Float16* Bb = BT + (long)b * bBS;

    const int n0 = nt * 128;
    const int m0 = mt * 128;
    const int tid  = threadIdx.x;
    const int wave = tid >> 6, lane = tid & 63;
    const int m16  = lane & 15, quad = lane >> 4;

    const int acol = (tid & 15) * 4;
    const int arb  = tid >> 4;
    const int bj   = tid >> 1;
    const int bcc  = (tid & 1) * 32;
    int jn = n0 + bj; if (jn > N - 1) jn = N - 1;
    const _Float16* bpB = Bb + (long)jn * ldbt;

    f32x4 acc[2][8];
    {
        f32x4 zz = {0.f, 0.f, 0.f, 0.f};
#pragma unroll
        for (int i = 0; i < 2; ++i)
#pragma unroll
            for (int j = 0; j < 8; ++j) acc[i][j] = zz;
    }

    for (int k0 = kbeg; k0 < kend; k0 += 64) {
        {
            const int cc = acol;
            float4 av[8];
#pragma unroll
            for (int p = 0; p < 8; ++p)
                av[p] = *(const float4*)(A + (long)(m0 + arb + p * 16) * lda + k0 + cc);
#pragma unroll
            for (int p = 0; p < 8; ++p) {
                half4 hv;
                hv[0] = (_Float16)av[p].x; hv[1] = (_Float16)av[p].y;
                hv[2] = (_Float16)av[p].z; hv[3] = (_Float16)av[p].w;
                *(half4*)&As[arb + p * 16][cc] = hv;
            }
        }
        {
            const _Float16* bp = bpB + k0 + bcc;
            half8 b0 = *(const half8*)(bp);
            half8 b1 = *(const half8*)(bp + 8);
            half8 b2 = *(const half8*)(bp + 16);
            half8 b3 = *(const half8*)(bp + 24);
            *(half8*)&Bs[bj][bcc]      = b0;
            *(half8*)&Bs[bj][bcc + 8]  = b1;
            *(half8*)&Bs[bj][bcc + 16] = b2;
            *(half8*)&Bs[bj][bcc + 24] = b3;
        }
        __syncthreads();
#pragma unroll
        for (int kss = 0; kss < 2; ++kss) {
            const int ko = kss * 32 + quad * 8;
            const half8 a0 = *(const half8*)&As[wave * 32 + m16][ko];
            const half8 a1 = *(const half8*)&As[wave * 32 + 16 + m16][ko];
#pragma unroll
            for (int c = 0; c < 8; ++c) {
                const half8 bf = *(const half8*)&Bs[c * 16 + m16][ko];
                acc[0][c] = MFMA16(a0, bf, acc[0][c]);
                acc[1][c] = MFMA16(a1, bf, acc[1][c]);
            }
        }
        __syncthreads();
    }

    const float* bias = b ? bias1 : bias0;
    const int addb = (bias != nullptr) && (kbeg == 0);
#pragma unroll
    for (int hh = 0; hh < 2; ++hh) {
#pragma unroll
        for (int c = 0; c < 8; ++c) {
            const int col = n0 + c * 16 + m16;
            if (col >= N) continue;
            const float bb = addb ? bias[col] : 0.f;
#pragma unroll
            for (int r = 0; r < 4; ++r) {
                const int row = m0 + wave * 32 + hh * 16 + quad * 4 + r;
                const float v = acc[hh][c][r] + bb;
                const long idx = (long)b * cBS + (long)row * ldc + col;
                if (atomic)      atomicAdd(&((float*)Cout)[idx], v);
                else if (c_half) ((_Float16*)Cout)[idx] = (_Float16)v;
                else             ((float*)Cout)[idx] = v;
            }
        }
    }
}

// ---------------------------------------------------------------------------
// Pass 1: per (b,h,s) row stats. R4: occupancy 2->4 blocks/CU (latency-bound
// stage->barrier->compute loop; more TLP hides the per-tile stage latency).
// ---------------------------------------------------------------------------
__global__ __launch_bounds__(256, 4) void attn_stats(
    const _Float16* __restrict__ q_all, const _Float16* __restrict__ k_all,
    float* __restrict__ m_out, float* __restrict__ il_out)
{
    const int st = blockIdx.x, h = blockIdx.y, b = blockIdx.z;
    const int tid = threadIdx.x, wave = tid >> 6, lane = tid & 63;
    const int m16 = lane & 15, quad = lane >> 4;
    const int s0 = st * 64;
    const int sw = s0 + wave * 16;

    __shared__ __align__(16) _Float16 qs[64][72];
    __shared__ __align__(16) _Float16 ks[64][72];

    const int srow = tid >> 2;
    const int scol = (tid & 3) * 16;

    {
        const _Float16* qsrc = q_all + ((long)(b * 1024 + s0 + srow)) * 1024 + h * 64 + scol;
        *(half8*)&qs[srow][scol]     = *(const half8*)(qsrc);
        *(half8*)&qs[srow][scol + 8] = *(const half8*)(qsrc + 8);
    }

    const _Float16* ksrcb = k_all + ((long)(b * 1024 + srow)) * 1024 + h * 64 + scol;

    float mr[4], lr[4];
#pragma unroll
    for (int r = 0; r < 4; ++r) { mr[r] = -3.0e38f; lr[r] = 0.f; }

    half8 a0, a1;
    for (int tt = 0; tt <= st; ++tt) {
        const _Float16* ksrc = ksrcb + (long)(tt * 64) * 1024;
        const half8 k0 = *(const half8*)(ksrc);
        const half8 k1 = *(const half8*)(ksrc + 8);

        __syncthreads();
        *(half8*)&ks[srow][scol]     = k0;
        *(half8*)&ks[srow][scol + 8] = k1;
        __syncthreads();

        if (tt == 0) {
            a0 = *(const half8*)&qs[wave * 16 + m16][quad * 8];
            a1 = *(const half8*)&qs[wave * 16 + m16][quad * 8 + 32];
        }

        if (tt < st) {
#pragma unroll
            for (int c = 0; c < 4; ++c) {
                const half8 b0 = *(const half8*)&ks[c * 16 + m16][quad * 8];
                const half8 b1 = *(const half8*)&ks[c * 16 + m16][quad * 8 + 32];
                f32x4 cc = {0.f, 0.f, 0.f, 0.f};
                cc = MFMA16(a0, b0, cc);
                cc = MFMA16(a1, b1, cc);
#pragma unroll
                for (int r = 0; r < 4; ++r) {
                    const float zz = cc[r] * 0.125f;
                    const float nm = fmaxf(mr[r], zz);
                    lr[r] = lr[r] * __expf(mr[r] - nm) + __expf(zz - nm);
                    mr[r] = nm;
                }
            }
        } else {
#pragma unroll
            for (int c = 0; c < 4; ++c) {
                const half8 b0 = *(const half8*)&ks[c * 16 + m16][quad * 8];
                const half8 b1 = *(const half8*)&ks[c * 16 + m16][quad * 8 + 32];
                f32x4 cc = {0.f, 0.f, 0.f, 0.f};
                cc = MFMA16(a0, b0, cc);
                cc = MFMA16(a1, b1, cc);
                const int col = tt * 64 + c * 16 + m16;
#pragma unroll
                for (int r = 0; r < 4; ++r) {
                    const int row = sw + quad * 4 + r;
                    if (col <= row) {
                        const float zz = cc[r] * 0.125f;
                        const float nm = fmaxf(mr[r], zz);
                        lr[r] = lr[r] * __expf(mr[r] - nm) + __expf(zz - nm);
                        mr[r] = nm;
                    }
                }
            }
        }
    }

#pragma unroll
    for (int mk = 1; mk < 16; mk <<= 1) {
#pragma unroll
        for (int r = 0; r < 4; ++r) {
            const float om = __shfl_xor(mr[r], mk);
            const float ol = __shfl_xor(lr[r], mk);
            const float nm = fmaxf(mr[r], om);
            lr[r] = lr[r] * __expf(mr[r] - nm) + ol * __expf(om - nm);
            mr[r] = nm;
        }
    }
    if (m16 == 0) {
#pragma unroll
        for (int r = 0; r < 4; ++r) {
            const long idx = ((long)(b * 16 + h)) * 1024 + sw + quad * 4 + r;
            m_out[idx]  = mr[r];
            il_out[idx] = 1.f / lr[r];
        }
    }
}

// ---------------------------------------------------------------------------
// Pass 2 R4: attn_mean + FUSED PV. After the h-loop, the block holds the
// 64x64 head-mean P tile in registers; instead of a separate split-K GEMM
// re-reading 16.8 MB fp32 attn, stash P as fp16 in LDS (numerically what the
// old ctx GEMM's A-conversion did), MFMA against vT B-fragments straight
// from L2 (V tile is 8 KB, hot), atomicAdd partial ctx. Eliminates one
// kernel + the attn round-trip. Occupancy 2->4 blocks/CU.
// ---------------------------------------------------------------------------
__global__ __launch_bounds__(256, 4) void attn_pmean(
    const _Float16* __restrict__ q_all, const _Float16* __restrict__ k_all,
    const float* __restrict__ m_in, const float* __restrict__ il_in,
    const _Float16* __restrict__ vT,     // [4][64][1024]
    float* __restrict__ attn,
    float* __restrict__ ctx)             // [4][1024][64], zero-init, atomic
{
    const int ttile = blockIdx.x, stile = blockIdx.y, b = blockIdx.z;
    const int tid = threadIdx.x;
    if (ttile > stile) {
        const int c4 = (tid & 15) * 4;
        float4 zz = {0.f, 0.f, 0.f, 0.f};
#pragma unroll
        for (int i = 0; i < 4; ++i) {
            const int r = stile * 64 + (tid >> 4) + i * 16;
            *(float4*)&attn[((long)(b * 1024 + r)) * 1024 + ttile * 64 + c4] = zz;
        }
        return;
    }

    __shared__ __align__(16) _Float16 qs[64][72];
    __shared__ __align__(16) _Float16 ks[64][72];
    __shared__ __align__(16) _Float16 ps[64][72];

    const int wave = tid >> 6, lane = tid & 63;
    const int m16 = lane & 15, quad = lane >> 4;
    const int s0 = stile * 64;
    const int t0 = ttile * 64;
    const int sw = s0 + wave * 16;
    const int diag = (ttile == stile);

    const int srow = tid >> 2;
    const int scol = (tid & 3) * 16;

    const _Float16* qsrc = q_all + ((long)(b * 1024 + s0 + srow)) * 1024 + scol;
    const _Float16* ksrc = k_all + ((long)(b * 1024 + t0 + srow)) * 1024 + scol;
    const long sbase = ((long)(b * 16)) * 1024 + sw + quad * 4;

    float pm[4][4];
#pragma unroll
    for (int c = 0; c < 4; ++c)
#pragma unroll
        for (int r = 0; r < 4; ++r) pm[c][r] = 0.f;

    for (int h = 0; h < 16; ++h) {
        const int ho = h * 64;
        const half8 q0 = *(const half8*)(qsrc + ho);
        const half8 q1 = *(const half8*)(qsrc + ho + 8);
        const half8 k0 = *(const half8*)(ksrc + ho);
        const half8 k1 = *(const half8*)(ksrc + ho + 8);
        const long idx = sbase + (long)h * 1024;
        const float4 mv = *(const float4*)&m_in[idx];
        const float4 iv = *(const float4*)&il_in[idx];

        __syncthreads();
        *(half8*)&qs[srow][scol]     = q0;
        *(half8*)&qs[srow][scol + 8] = q1;
        *(half8*)&ks[srow][scol]     = k0;
        *(half8*)&ks[srow][scol + 8] = k1;
        __syncthreads();

        const half8 a0 = *(const half8*)&qs[wave * 16 + m16][quad * 8];
        const half8 a1 = *(const half8*)&qs[wave * 16 + m16][quad * 8 + 32];
        const float mrow[4] = {mv.x, mv.y, mv.z, mv.w};
        const float irow[4] = {iv.x, iv.y, iv.z, iv.w};

        if (!diag) {
#pragma unroll
            for (int c = 0; c < 4; ++c) {
                const half8 b0 = *(const half8*)&ks[c * 16 + m16][quad * 8];
                const half8 b1 = *(const half8*)&ks[c * 16 + m16][quad * 8 + 32];
                f32x4 cc = {0.f, 0.f, 0.f, 0.f};
                cc = MFMA16(a0, b0, cc);
                cc = MFMA16(a1, b1, cc);
#pragma unroll
                for (int r = 0; r < 4; ++r)
                    pm[c][r] += __expf(cc[r] * 0.125f - mrow[r]) * irow[r];
            }
        } else {
#pragma unroll
            for (int c = 0; c < 4; ++c) {
                const half8 b0 = *(const half8*)&ks[c * 16 + m16][quad * 8];
                const half8 b1 = *(const half8*)&ks[c * 16 + m16][quad * 8 + 32];
                f32x4 cc = {0.f, 0.f, 0.f, 0.f};
                cc = MFMA16(a0, b0, cc);
                cc = MFMA16(a1, b1, cc);
                const int col = t0 + c * 16 + m16;
#pragma unroll
                for (int r = 0; r < 4; ++r) {
                    const int row = sw + quad * 4 + r;
                    if (col <= row)
                        pm[c][r] += __expf(cc[r] * 0.125f - mrow[r]) * irow[r];
                }
            }
        }
    }

    // attn write + P-tile stash (fp16 -- same quantization the old ctx GEMM
    // applied when converting its fp32 A to MFMA fragments)
#pragma unroll
    for (int c = 0; c < 4; ++c) {
#pragma unroll
        for (int r = 0; r < 4; ++r) {
            const int rloc = (wave << 4) + (quad << 2) + r;   // row within tile
            const int cloc = c * 16 + m16;                    // col within tile
            const float p = pm[c][r] * 0.0625f;
            attn[((long)(b * 1024 + s0 + rloc)) * 1024 + t0 + cloc] = p;
            ps[rloc][cloc] = (_Float16)p;
        }
    }
    __syncthreads();

    // PV: ctx[s][e] += sum_t P[s][t] * vT[e][t]
    const _Float16* vTb = vT + (long)b * 65536 + t0;   // + e*1024 + t
    f32x4 apv[4];
    {
        f32x4 zz = {0.f, 0.f, 0.f, 0.f};
#pragma unroll
        for (int c = 0; c < 4; ++c) apv[c] = zz;
    }
#pragma unroll
    for (int kss = 0; kss < 2; ++kss) {
        const half8 a = *(const half8*)&ps[wave * 16 + m16][kss * 32 + quad * 8];
#pragma unroll
        for (int c = 0; c < 4; ++c) {
            const half8 bf = *(const half8*)(vTb + (long)(c * 16 + m16) * 1024 + kss * 32 + quad * 8);
            apv[c] = MFMA16(a, bf, apv[c]);
        }
    }
#pragma unroll
    for (int c = 0; c < 4; ++c) {
#pragma unroll
        for (int r = 0; r < 4; ++r) {
            const int row = sw + quad * 4 + r;
            const int e   = c * 16 + m16;
            atomicAdd(&ctx[((long)(b * 1024 + row)) * 64 + e], apv[c][r]);
        }
    }
}

// ---------------------------------------------------------------------------
extern "C" void kernel_launch(void* const* d_in, const int* in_sizes, int n_in,
                              void* d_out, int out_size, void* d_ws, size_t ws_size,
                              hipStream_t stream)
{
    const float* queries = (const float*)d_in[0];
    const float* keys    = (const float*)d_in[1];
    const float* values  = (const float*)d_in[2];
    const float* Wq = (const float*)d_in[4];
    const float* bq = (const float*)d_in[5];
    const float* Wk = (const float*)d_in[6];
    const float* bk = (const float*)d_in[7];
    const float* Wv = (const float*)d_in[8];
    const float* bv = (const float*)d_in[9];
    const float* Wo = (const float*)d_in[10];
    const float* bo = (const float*)d_in[11];

    float* out_ptr  = (float*)d_out;                   // [4096][1024]
    float* attn_ptr = out_ptr + (long)4096 * 1024;     // [4][1024][1024]

    uint8_t* w = (uint8_t*)d_ws;
    size_t off = 0;
    auto alloc = [&](size_t bytes) {
        void* p = w + off;
        off = (off + bytes + 255) & ~(size_t)255;
        return p;
    };
    _Float16* WqkT  = (_Float16*)alloc((size_t)2 * 1024 * 1024 * 2); // WqT|WkT [n][d]
    _Float16* WvT   = (_Float16*)alloc((size_t)64 * 1024 * 2);       // [e][d]
    _Float16* WoT   = (_Float16*)alloc((size_t)1024 * 64 * 2);       // [d][e]
    _Float16* qkall = (_Float16*)alloc((size_t)2 * 4194304 * 2);     // qall|kall
    _Float16* a16   = (_Float16*)alloc((size_t)2 * 4194304 * 2);     // q16|k16 inputs
    float*    vbuf  = (float*)alloc((size_t)4096 * 64 * 4);
    _Float16* vT    = (_Float16*)alloc((size_t)4 * 64 * 1024 * 2);   // per-b [e][t]
    float*    ctx   = (float*)alloc((size_t)4096 * 64 * 4);
    float*    mbuf  = (float*)alloc((size_t)65536 * 4);
    float*    ilbuf = (float*)alloc((size_t)65536 * 4);
    (void)ws_size; (void)in_sizes; (void)n_in; (void)out_size;

    _Float16* qall = qkall;
    _Float16* kall = qkall + (long)4194304;

    // weight transposes/conversions + activation fp16 convert
    transpose_to_f16<<<dim3(2, 32, 16), 256, 0, stream>>>(Wq, WqkT, 1024, 64, 65536, 65536);
    transpose_to_f16<<<dim3(2, 32, 16), 256, 0, stream>>>(Wk, WqkT + (long)1024 * 1024, 1024, 64, 65536, 65536);
    transpose_to_f16<<<dim3(2, 32, 1),  256, 0, stream>>>(Wv, WvT, 1024, 64, 0, 0);
    transpose_to_f16<<<dim3(32, 2, 1),  256, 0, stream>>>(Wo, WoT, 64, 1024, 0, 0);
    cvt_qk_f16<<<dim3(2048, 2, 1), 256, 0, stream>>>(queries, keys, a16);

    // fused q+k projection: glds 2-phase double-buffered kernel
    gemm_qk_glds<<<dim3(8, 32, 2), 256, 0, stream>>>(
        a16, WqkT, bq, bk, qkall);

    // v projection: split-K x8 atomic into vbuf (zeroed) -> 256 blocks
    hipMemsetAsync(vbuf, 0, (size_t)4096 * 64 * 4, stream);
    gemm_f16_v2<<<dim3(1, 32, 8), 256, 0, stream>>>(
        values, nullptr, WvT, bv, nullptr, vbuf,
        64, 1024, 1024, 64,
        0, 0, 0,
        /*c_half=*/0, /*atomic=*/1, /*nks=*/8, /*kchunk=*/128);

    // vT per batch: [1024][64] -> [64][1024] fp16
    transpose_to_f16<<<dim3(2, 32, 4), 256, 0, stream>>>(vbuf, vT, 1024, 64, 65536, 65536);

    // softmax stats, then head-mean probabilities + fused PV into ctx
    hipMemsetAsync(ctx, 0, (size_t)4096 * 64 * 4, stream);
    attn_stats<<<dim3(16, 16, 4), 256, 0, stream>>>(qall, kall, mbuf, ilbuf);
    attn_pmean<<<dim3(16, 16, 4), 256, 0, stream>>>(qall, kall, mbuf, ilbuf, vT, attn_ptr, ctx);

    // out = ctx @ Wo + bo (K=64: single iteration)
    gemm_f16_v2<<<dim3(8, 32, 1), 256, 0, stream>>>(
        ctx, nullptr, WoT, bo, nullptr, out_ptr,
        1024, 64, 64, 1024,
        0, 0, 0,
        /*c_half=*/0, /*atomic=*/0, /*nks=*/1, /*kchunk=*/64);
}

// Round 5
// 241.482 us; speedup vs baseline: 1.0642x; 1.0013x over previous
//
#include <hip/hip_runtime.h>
#include <hip/hip_bf16.h>
#include <stdint.h>

typedef _Float16 half8 __attribute__((ext_vector_type(8)));
typedef _Float16 half4 __attribute__((ext_vector_type(4)));
typedef float    f32x4 __attribute__((ext_vector_type(4)));

#define MFMA16(a, b, c) __builtin_amdgcn_mfma_f32_16x16x32_f16(a, b, c, 0, 0, 0)

// global_load_lds helper: 16B per lane, LDS dest = wave-uniform base + lane*16.
typedef __attribute__((address_space(1))) const void GVOID;
typedef __attribute__((address_space(3))) void LVOID;
__device__ __forceinline__ void glds16(const void* g, void* l)
{
    __builtin_amdgcn_global_load_lds((GVOID*)g, (LVOID*)l, 16, 0, 0);
}

// raw barrier with compiler memory fences (builtin s_barrier alone is not a
// compiler code-motion fence)
#define BARRIER() do { asm volatile("" ::: "memory"); \
    __builtin_amdgcn_s_barrier(); \
    asm volatile("" ::: "memory"); } while (0)

// ---------------------------------------------------------------------------
// Generic fp32->fp16 transpose: X [R][C] fp32 -> Y [C][R] fp16, z-batched.
// ---------------------------------------------------------------------------
__global__ __launch_bounds__(256) void transpose_to_f16(
    const float* __restrict__ X, _Float16* __restrict__ Y,
    int R, int C, long inBS, long outBS)
{
    __shared__ float t[32][33];
    const int bz = blockIdx.z;
    X += (long)bz * inBS;
    Y += (long)bz * outBS;
    const int c0 = blockIdx.x * 32, r0 = blockIdx.y * 32;
    const int tx = threadIdx.x & 31, ty = threadIdx.x >> 5;
#pragma unroll
    for (int i = 0; i < 4; ++i)
        t[ty + i * 8][tx] = X[(long)(r0 + ty + i * 8) * C + c0 + tx];
    __syncthreads();
#pragma unroll
    for (int i = 0; i < 4; ++i)
        Y[(long)(c0 + ty + i * 8) * R + r0 + tx] = (_Float16)t[tx][ty + i * 8];
}

// ---------------------------------------------------------------------------
// fp32 -> fp16 convert for q/k activations.
// ---------------------------------------------------------------------------
__global__ __launch_bounds__(256) void cvt_qk_f16(
    const float* __restrict__ S0, const float* __restrict__ S1,
    _Float16* __restrict__ D)
{
    const float* S = blockIdx.y ? S1 : S0;
    _Float16* Dz = D + (long)blockIdx.y * 4194304;
    const long i = ((long)blockIdx.x * 256 + threadIdx.x) * 8;
    const float4 v0 = *(const float4*)(S + i);
    const float4 v1 = *(const float4*)(S + i + 4);
    half8 h;
    h[0] = (_Float16)v0.x; h[1] = (_Float16)v0.y;
    h[2] = (_Float16)v0.z; h[3] = (_Float16)v0.w;
    h[4] = (_Float16)v1.x; h[5] = (_Float16)v1.y;
    h[6] = (_Float16)v1.z; h[7] = (_Float16)v1.w;
    *(half8*)(Dz + i) = h;
}

// ---------------------------------------------------------------------------
// q+k projection GEMM R5: glds + counted-vmcnt 2-buffer pipeline (T4).
// R3/R4's __syncthreads drained vmcnt(0) every K-step -> the prefetch issued
// that step was serialized at the barrier. Now: prologue stages 2 tiles; each
// step waits vmcnt(8) (= keep newest stage's 8 glds in flight), raw barrier,
// compute, barrier, restage. Loads span TWO compute phases. Tail: vmcnt(0).
// ---------------------------------------------------------------------------
__global__ __launch_bounds__(256, 2) void gemm_qk_glds(
    const _Float16* __restrict__ A16,   // [2][4096][1024] fp16 (q16|k16)
    const _Float16* __restrict__ BT,    // [2][1024][1024] fp16 (WqT|WkT)
    const float* __restrict__ bias0, const float* __restrict__ bias1,
    _Float16* __restrict__ Cout)        // [2][4096][1024] fp16 (qall|kall)
{
    __shared__ __align__(16) _Float16 As[2][128 * 64];
    __shared__ __align__(16) _Float16 Bs[2][128 * 64];

    const int gx  = gridDim.x, gy = gridDim.y;
    const int nwg = gx * gy * (int)gridDim.z;
    const int lid = (int)blockIdx.x + gx * ((int)blockIdx.y + gy * (int)blockIdx.z);
    const int q8  = nwg >> 3;
    const int xcd = lid & 7, loc = lid >> 3;
    const int sw  = xcd * q8 + loc;
    const int nt  = sw % gx;
    const int tm2 = sw / gx;
    const int mt  = tm2 % gy;
    const int z   = tm2 / gy;           // 0 = q, 1 = k

    const int n0 = nt * 128;
    const int m0 = mt * 128;
    const int tid  = threadIdx.x;
    const int wave = tid >> 6, lane = tid & 63;
    const int m16  = lane & 15, quad = lane >> 4;

    const char* Az = (const char*)(A16 + (long)z * 4194304);
    const char* Bz = (const char*)(BT  + (long)z * 1048576);

    const int colbyte = (((lane & 7) ^ (lane >> 3)) << 4);
    const char* gaBase = Az + ((long)(m0 + wave * 32 + (lane >> 3)) << 11) + colbyte;
    const char* gbBase = Bz + ((long)(n0 + wave * 32 + (lane >> 3)) << 11) + colbyte;

    f32x4 acc[2][8];
    {
        f32x4 zz = {0.f, 0.f, 0.f, 0.f};
#pragma unroll
        for (int i = 0; i < 2; ++i)
#pragma unroll
            for (int j = 0; j < 8; ++j) acc[i][j] = zz;
    }

    auto STAGE = [&](int bf, int k0) {   // 8 glds / thread
        const char* ga = gaBase + (k0 << 1);
        const char* gb = gbBase + (k0 << 1);
        _Float16* la = &As[bf][wave * 32 * 64];
        _Float16* lb = &Bs[bf][wave * 32 * 64];
#pragma unroll
        for (int i = 0; i < 4; ++i) {
            glds16(ga + (long)i * 8 * 2048, la + i * 8 * 64);
            glds16(gb + (long)i * 8 * 2048, lb + i * 8 * 64);
        }
    };

    auto COMPUTE = [&](int bf) {
        const char* Ab = (const char*)&As[bf][0];
        const char* Bp = (const char*)&Bs[bf][0];
        const int sw4 = (m16 & 7) << 4;
#pragma unroll
        for (int kss = 0; kss < 2; ++kss) {
            const int kbs = (kss * 64 + quad * 16) ^ sw4;
            const half8 a0 = *(const half8*)(Ab + (wave * 32 + m16) * 128 + kbs);
            const half8 a1 = *(const half8*)(Ab + (wave * 32 + 16 + m16) * 128 + kbs);
#pragma unroll
            for (int c = 0; c < 8; ++c) {
                const half8 bfr = *(const half8*)(Bp + (c * 16 + m16) * 128 + kbs);
                acc[0][c] = MFMA16(a0, bfr, acc[0][c]);
                acc[1][c] = MFMA16(a1, bfr, acc[1][c]);
            }
        }
    };

    STAGE(0, 0);
    STAGE(1, 64);                         // 16 glds in flight
    int cur = 0;
    for (int t = 0; t < 15; ++t) {
        // stage t landed iff <=8 outstanding (only stage t+1 may remain)
        asm volatile("s_waitcnt vmcnt(8)" ::: "memory");
        __builtin_amdgcn_sched_barrier(0);
        BARRIER();                        // all waves' stage t landed
        COMPUTE(cur);
        BARRIER();                        // all waves done reading buf cur
        if (t < 14) STAGE(cur, (t + 2) * 64);
        cur ^= 1;
    }
    asm volatile("s_waitcnt vmcnt(0)" ::: "memory");
    __builtin_amdgcn_sched_barrier(0);
    BARRIER();
    COMPUTE(cur);

    const float* bias = z ? bias1 : bias0;
    _Float16* Cz = Cout + (long)z * 4194304;
#pragma unroll
    for (int hh = 0; hh < 2; ++hh) {
#pragma unroll
        for (int c = 0; c < 8; ++c) {
            const int col = n0 + c * 16 + m16;
            const float bb = bias[col];
#pragma unroll
            for (int r = 0; r < 4; ++r) {
                const int row = m0 + wave * 32 + hh * 16 + quad * 4 + r;
                Cz[(long)row * 1024 + col] = (_Float16)(acc[hh][c][r] + bb);
            }
        }
    }
}

// ---------------------------------------------------------------------------
// MFMA GEMM (fp32 A path) — v-proj / out (unchanged from R4-passing).
// ---------------------------------------------------------------------------
__global__ __launch_bounds__(256, 2) void gemm_f16_v2(
    const float* __restrict__ A0, const float* __restrict__ A1,
    const _Float16* __restrict__ BT,
    const float* __restrict__ bias0, const float* __restrict__ bias1,
    void* __restrict__ Cout,
    int N, int lda, int ldbt, int ldc,
    long aBS, long bBS, long cBS,
    int c_half, int atomic, int nks, int kchunk)
{
    __shared__ __align__(16) _Float16 As[128][72];
    __shared__ __align__(16) _Float16 Bs[128][72];

    const int gx  = gridDim.x, gy = gridDim.y;
    const int nwg = gx * gy * (int)gridDim.z;
    const int lid = (int)blockIdx.x + gx * ((int)blockIdx.y + gy * (int)blockIdx.z);
    const int q8  = nwg >> 3, r8 = nwg & 7;
    const int xcd = lid & 7, loc = lid >> 3;
    const int sw  = (xcd < r8 ? xcd * (q8 + 1) : r8 * (q8 + 1) + (xcd - r8) * q8) + loc;
    const int nt  = sw % gx;
    const int tm2 = sw / gx;
    const int mt  = tm2 % gy;
    const int bz  = tm2 / gy;

    const int b = bz / nks, ks = bz % nks;
    const int kbeg = ks * kchunk;
    const int kend = kbeg + kchunk;

    const float* A = A1 ? (b ? A1 : A0) : (A0 + (long)b * aBS);
    const _Float16* Bb = BT + (long)b * bBS;

    const int n0 = nt * 128;
    const int m0 = mt * 128;
    const int tid  = threadIdx.x;
    const int wave = tid >> 6, lane = tid & 63;
    const int m16  = lane & 15, quad = lane >> 4;

    const int acol = (tid & 15) * 4;
    const int arb  = tid >> 4;
    const int bj   = tid >> 1;
    const int bcc  = (tid & 1) * 32;
    int jn = n0 + bj; if (jn > N - 1) jn = N - 1;
    const _Float16* bpB = Bb + (long)jn * ldbt;

    f32x4 acc[2][8];
    {
        f32x4 zz = {0.f, 0.f, 0.f, 0.f};
#pragma unroll
        for (int i = 0; i < 2; ++i)
#pragma unroll
            for (int j = 0; j < 8; ++j) acc[i][j] = zz;
    }

    for (int k0 = kbeg; k0 < kend; k0 += 64) {
        {
            float4 av[8];
#pragma unroll
            for (int p = 0; p < 8; ++p)
                av[p] = *(const float4*)(A + (long)(m0 + arb + p * 16) * lda + k0 + acol);
#pragma unroll
            for (int p = 0; p < 8; ++p) {
                half4 hv;
                hv[0] = (_Float16)av[p].x; hv[1] = (_Float16)av[p].y;
                hv[2] = (_Float16)av[p].z; hv[3] = (_Float16)av[p].w;
                *(half4*)&As[arb + p * 16][acol] = hv;
            }
        }
        {
            const _Float16* bp = bpB + k0 + bcc;
            half8 b0 = *(const half8*)(bp);
            half8 b1 = *(const half8*)(bp + 8);
            half8 b2 = *(const half8*)(bp + 16);
            half8 b3 = *(const half8*)(bp + 24);
            *(half8*)&Bs[bj][bcc]      = b0;
            *(half8*)&Bs[bj][bcc + 8]  = b1;
            *(half8*)&Bs[bj][bcc + 16] = b2;
            *(half8*)&Bs[bj][bcc + 24] = b3;
        }
        __syncthreads();
#pragma unroll
        for (int kss = 0; kss < 2; ++kss) {
            const int ko = kss * 32 + quad * 8;
            const half8 a0 = *(const half8*)&As[wave * 32 + m16][ko];
            const half8 a1 = *(const half8*)&As[wave * 32 + 16 + m16][ko];
#pragma unroll
            for (int c = 0; c < 8; ++c) {
                const half8 bf = *(const half8*)&Bs[c * 16 + m16][ko];
                acc[0][c] = MFMA16(a0, bf, acc[0][c]);
                acc[1][c] = MFMA16(a1, bf, acc[1][c]);
            }
        }
        __syncthreads();
    }

    const float* bias = b ? bias1 : bias0;
    const int addb = (bias != nullptr) && (kbeg == 0);
#pragma unroll
    for (int hh = 0; hh < 2; ++hh) {
#pragma unroll
        for (int c = 0; c < 8; ++c) {
            const int col = n0 + c * 16 + m16;
            if (col >= N) continue;
            const float bb = addb ? bias[col] : 0.f;
#pragma unroll
            for (int r = 0; r < 4; ++r) {
                const int row = m0 + wave * 32 + hh * 16 + quad * 4 + r;
                const float v = acc[hh][c][r] + bb;
                const long idx = (long)b * cBS + (long)row * ldc + col;
                if (atomic)      atomicAdd(&((float*)Cout)[idx], v);
                else if (c_half) ((_Float16*)Cout)[idx] = (_Float16)v;
                else             ((float*)Cout)[idx] = v;
            }
        }
    }
}

// ---------------------------------------------------------------------------
// Pass 1: per (b,h,s) row stats (unchanged from R4-passing).
// ---------------------------------------------------------------------------
__global__ __launch_bounds__(256, 4) void attn_stats(
    const _Float16* __restrict__ q_all, const _Float16* __restrict__ k_all,
    float* __restrict__ m_out, float* __restrict__ il_out)
{
    const int st = blockIdx.x, h = blockIdx.y, b = blockIdx.z;
    const int tid = threadIdx.x, wave = tid >> 6, lane = tid & 63;
    const int m16 = lane & 15, quad = lane >> 4;
    const int s0 = st * 64;
    const int sw = s0 + wave * 16;

    __shared__ __align__(16) _Float16 qs[64][72];
    __shared__ __align__(16) _Float16 ks[64][72];

    const int srow = tid >> 2;
    const int scol = (tid & 3) * 16;

    {
        const _Float16* qsrc = q_all + ((long)(b * 1024 + s0 + srow)) * 1024 + h * 64 + scol;
        *(half8*)&qs[srow][scol]     = *(const half8*)(qsrc);
        *(half8*)&qs[srow][scol + 8] = *(const half8*)(qsrc + 8);
    }

    const _Float16* ksrcb = k_all + ((long)(b * 1024 + srow)) * 1024 + h * 64 + scol;

    float mr[4], lr[4];
#pragma unroll
    for (int r = 0; r < 4; ++r) { mr[r] = -3.0e38f; lr[r] = 0.f; }

    half8 a0, a1;
    for (int tt = 0; tt <= st; ++tt) {
        const _Float16* ksrc = ksrcb + (long)(tt * 64) * 1024;
        const half8 k0 = *(const half8*)(ksrc);
        const half8 k1 = *(const half8*)(ksrc + 8);

        __syncthreads();
        *(half8*)&ks[srow][scol]     = k0;
        *(half8*)&ks[srow][scol + 8] = k1;
        __syncthreads();

        if (tt == 0) {
            a0 = *(const half8*)&qs[wave * 16 + m16][quad * 8];
            a1 = *(const half8*)&qs[wave * 16 + m16][quad * 8 + 32];
        }

        if (tt < st) {
#pragma unroll
            for (int c = 0; c < 4; ++c) {
                const half8 b0 = *(const half8*)&ks[c * 16 + m16][quad * 8];
                const half8 b1 = *(const half8*)&ks[c * 16 + m16][quad * 8 + 32];
                f32x4 cc = {0.f, 0.f, 0.f, 0.f};
                cc = MFMA16(a0, b0, cc);
                cc = MFMA16(a1, b1, cc);
#pragma unroll
                for (int r = 0; r < 4; ++r) {
                    const float zz = cc[r] * 0.125f;
                    const float nm = fmaxf(mr[r], zz);
                    lr[r] = lr[r] * __expf(mr[r] - nm) + __expf(zz - nm);
                    mr[r] = nm;
                }
            }
        } else {
#pragma unroll
            for (int c = 0; c < 4; ++c) {
                const half8 b0 = *(const half8*)&ks[c * 16 + m16][quad * 8];
                const half8 b1 = *(const half8*)&ks[c * 16 + m16][quad * 8 + 32];
                f32x4 cc = {0.f, 0.f, 0.f, 0.f};
                cc = MFMA16(a0, b0, cc);
                cc = MFMA16(a1, b1, cc);
                const int col = tt * 64 + c * 16 + m16;
#pragma unroll
                for (int r = 0; r < 4; ++r) {
                    const int row = sw + quad * 4 + r;
                    if (col <= row) {
                        const float zz = cc[r] * 0.125f;
                        const float nm = fmaxf(mr[r], zz);
                        lr[r] = lr[r] * __expf(mr[r] - nm) + __expf(zz - nm);
                        mr[r] = nm;
                    }
                }
            }
        }
    }

#pragma unroll
    for (int mk = 1; mk < 16; mk <<= 1) {
#pragma unroll
        for (int r = 0; r < 4; ++r) {
            const float om = __shfl_xor(mr[r], mk);
            const float ol = __shfl_xor(lr[r], mk);
            const float nm = fmaxf(mr[r], om);
            lr[r] = lr[r] * __expf(mr[r] - nm) + ol * __expf(om - nm);
            mr[r] = nm;
        }
    }
    if (m16 == 0) {
#pragma unroll
        for (int r = 0; r < 4; ++r) {
            const long idx = ((long)(b * 16 + h)) * 1024 + sw + quad * 4 + r;
            m_out[idx]  = mr[r];
            il_out[idx] = 1.f / lr[r];
        }
    }
}

// ---------------------------------------------------------------------------
// Pass 2 R5: head-mean softmax + fused PV, now with glds-staged q/k tiles
// and the counted-vmcnt 2-buffer pipeline (same schedule as gemm_qk_glds).
// m/il stats are pre-staged into an LDS table (ds_read in-loop) so the
// manual vmcnt counting sees ONLY the 4 glds per stage.
// LDS: 2x8KB q + 2x8KB k + ps 9.2KB + 8KB stats = 49.2KB -> 3 blocks/CU.
// ---------------------------------------------------------------------------
__global__ __launch_bounds__(256, 3) void attn_pmean(
    const _Float16* __restrict__ q_all, const _Float16* __restrict__ k_all,
    const float* __restrict__ m_in, const float* __restrict__ il_in,
    const _Float16* __restrict__ vT,     // [4][64][1024]
    float* __restrict__ attn,
    float* __restrict__ ctx)             // [4][1024][64], zero-init, atomic
{
    const int ttile = blockIdx.x, stile = blockIdx.y, b = blockIdx.z;
    const int tid = threadIdx.x;
    if (ttile > stile) {
        const int c4 = (tid & 15) * 4;
        float4 zz = {0.f, 0.f, 0.f, 0.f};
#pragma unroll
        for (int i = 0; i < 4; ++i) {
            const int r = stile * 64 + (tid >> 4) + i * 16;
            *(float4*)&attn[((long)(b * 1024 + r)) * 1024 + ttile * 64 + c4] = zz;
        }
        return;
    }

    __shared__ __align__(16) _Float16 qs2[2][64 * 64];
    __shared__ __align__(16) _Float16 ks2[2][64 * 64];
    __shared__ __align__(16) _Float16 ps[64][72];
    __shared__ __align__(16) float mls[16][64];
    __shared__ __align__(16) float ils[16][64];

    const int wave = tid >> 6, lane = tid & 63;
    const int m16 = lane & 15, quad = lane >> 4;
    const int s0 = stile * 64;
    const int t0 = ttile * 64;
    const int sw = s0 + wave * 16;
    const int diag = (ttile == stile);

    // ---- stats table: one coalesced pull, then vmcnt-clean ds_reads ----
    {
        const int hh = tid >> 4;            // 0..15
        const int c4 = (tid & 15) * 4;      // 0..60
        const long ix = ((long)(b * 16 + hh)) * 1024 + s0 + c4;
        const float4 mv4 = *(const float4*)&m_in[ix];
        const float4 iv4 = *(const float4*)&il_in[ix];
        *(float4*)&mls[hh][c4] = mv4;
        *(float4*)&ils[hh][c4] = iv4;
    }

    // ---- glds staging: swizzled source, linear LDS (rule #21 pair) ----
    const int colb = (((lane & 7) ^ (lane >> 3)) << 4);
    const char* gq = (const char*)q_all + ((long)(b * 1024 + s0 + wave * 16 + (lane >> 3)) << 11) + colb;
    const char* gk = (const char*)k_all + ((long)(b * 1024 + t0 + wave * 16 + (lane >> 3)) << 11) + colb;

    auto STAGE_P = [&](int bf, int h) {   // 4 glds / thread
        const char* q = gq + h * 128;
        const char* k = gk + h * 128;
        _Float16* lq = &qs2[bf][wave * 16 * 64];
        _Float16* lk = &ks2[bf][wave * 16 * 64];
        glds16(q, lq);
        glds16(q + 8 * 2048, lq + 8 * 64);
        glds16(k, lk);
        glds16(k + 8 * 2048, lk + 8 * 64);
    };

    STAGE_P(0, 0);
    STAGE_P(1, 1);                        // 8 glds in flight
    asm volatile("s_waitcnt lgkmcnt(0)" ::: "memory");   // mls/ils written
    BARRIER();                            // table visible to all waves

    float pm[4][4];
#pragma unroll
    for (int c = 0; c < 4; ++c)
#pragma unroll
        for (int r = 0; r < 4; ++r) pm[c][r] = 0.f;

    const int swz = (m16 & 7) << 4;
    int cur = 0;

    auto COMPUTE_H = [&](int h, int bf) {
        const char* Qc = (const char*)&qs2[bf][0];
        const char* Kc = (const char*)&ks2[bf][0];
        const half8 a0 = *(const half8*)(Qc + (wave * 16 + m16) * 128 + ((quad * 16) ^ swz));
        const half8 a1 = *(const half8*)(Qc + (wave * 16 + m16) * 128 + ((quad * 16 + 64) ^ swz));
        const float4 mv = *(const float4*)&mls[h][wave * 16 + quad * 4];
        const float4 iv = *(const float4*)&ils[h][wave * 16 + quad * 4];
        const float mrow[4] = {mv.x, mv.y, mv.z, mv.w};
        const float irow[4] = {iv.x, iv.y, iv.z, iv.w};
        if (!diag) {
#pragma unroll
            for (int c = 0; c < 4; ++c) {
                const half8 b0 = *(const half8*)(Kc + (c * 16 + m16) * 128 + ((quad * 16) ^ swz));
                const half8 b1 = *(const half8*)(Kc + (c * 16 + m16) * 128 + ((quad * 16 + 64) ^ swz));
                f32x4 cc = {0.f, 0.f, 0.f, 0.f};
                cc = MFMA16(a0, b0, cc);
                cc = MFMA16(a1, b1, cc);
#pragma unroll
                for (int r = 0; r < 4; ++r)
                    pm[c][r] += __expf(cc[r] * 0.125f - mrow[r]) * irow[r];
            }
        } else {
#pragma unroll
            for (int c = 0; c < 4; ++c) {
                const half8 b0 = *(const half8*)(Kc + (c * 16 + m16) * 128 + ((quad * 16) ^ swz));
                const half8 b1 = *(const half8*)(Kc + (c * 16 + m16) * 128 + ((quad * 16 + 64) ^ swz));
                f32x4 cc = {0.f, 0.f, 0.f, 0.f};
                cc = MFMA16(a0, b0, cc);
                cc = MFMA16(a1, b1, cc);
                const int col = t0 + c * 16 + m16;
#pragma unroll
                for (int r = 0; r < 4; ++r) {
                    const int row = sw + quad * 4 + r;
                    if (col <= row)
                        pm[c][r] += __expf(cc[r] * 0.125f - mrow[r]) * irow[r];
                }
            }
        }
    };

    for (int h = 0; h < 15; ++h) {
        asm volatile("s_waitcnt vmcnt(4)" ::: "memory");   // stage h landed
        __builtin_amdgcn_sched_barrier(0);
        BARRIER();
        COMPUTE_H(h, cur);
        BARRIER();
        if (h < 14) STAGE_P(cur, h + 2);
        cur ^= 1;
    }
    asm volatile("s_waitcnt vmcnt(0)" ::: "memory");
    __builtin_amdgcn_sched_barrier(0);
    BARRIER();
    COMPUTE_H(15, cur);

    // attn write + P-tile stash (fp16)
#pragma unroll
    for (int c = 0; c < 4; ++c) {
#pragma unroll
        for (int r = 0; r < 4; ++r) {
            const int rloc = (wave << 4) + (quad << 2) + r;
            const int cloc = c * 16 + m16;
            const float p = pm[c][r] * 0.0625f;
            attn[((long)(b * 1024 + s0 + rloc)) * 1024 + t0 + cloc] = p;
            ps[rloc][cloc] = (_Float16)p;
        }
    }
    __syncthreads();

    // PV: ctx[s][e] += sum_t P[s][t] * vT[e][t]
    const _Float16* vTb = vT + (long)b * 65536 + t0;
    f32x4 apv[4];
    {
        f32x4 zz = {0.f, 0.f, 0.f, 0.f};
#pragma unroll
        for (int c = 0; c < 4; ++c) apv[c] = zz;
    }
#pragma unroll
    for (int kss = 0; kss < 2; ++kss) {
        const half8 a = *(const half8*)&ps[wave * 16 + m16][kss * 32 + quad * 8];
#pragma unroll
        for (int c = 0; c < 4; ++c) {
            const half8 bf = *(const half8*)(vTb + (long)(c * 16 + m16) * 1024 + kss * 32 + quad * 8);
            apv[c] = MFMA16(a, bf, apv[c]);
        }
    }
#pragma unroll
    for (int c = 0; c < 4; ++c) {
#pragma unroll
        for (int r = 0; r < 4; ++r) {
            const int row = sw + quad * 4 + r;
            const int e   = c * 16 + m16;
            atomicAdd(&ctx[((long)(b * 1024 + row)) * 64 + e], apv[c][r]);
        }
    }
}

// ---------------------------------------------------------------------------
extern "C" void kernel_launch(void* const* d_in, const int* in_sizes, int n_in,
                              void* d_out, int out_size, void* d_ws, size_t ws_size,
                              hipStream_t stream)
{
    const float* queries = (const float*)d_in[0];
    const float* keys    = (const float*)d_in[1];
    const float* values  = (const float*)d_in[2];
    const float* Wq = (const float*)d_in[4];
    const float* bq = (const float*)d_in[5];
    const float* Wk = (const float*)d_in[6];
    const float* bk = (const float*)d_in[7];
    const float* Wv = (const float*)d_in[8];
    const float* bv = (const float*)d_in[9];
    const float* Wo = (const float*)d_in[10];
    const float* bo = (const float*)d_in[11];

    float* out_ptr  = (float*)d_out;                   // [4096][1024]
    float* attn_ptr = out_ptr + (long)4096 * 1024;     // [4][1024][1024]

    uint8_t* w = (uint8_t*)d_ws;
    size_t off = 0;
    auto alloc = [&](size_t bytes) {
        void* p = w + off;
        off = (off + bytes + 255) & ~(size_t)255;
        return p;
    };
    _Float16* WqkT  = (_Float16*)alloc((size_t)2 * 1024 * 1024 * 2); // WqT|WkT [n][d]
    _Float16* WvT   = (_Float16*)alloc((size_t)64 * 1024 * 2);       // [e][d]
    _Float16* WoT   = (_Float16*)alloc((size_t)1024 * 64 * 2);       // [d][e]
    _Float16* qkall = (_Float16*)alloc((size_t)2 * 4194304 * 2);     // qall|kall
    _Float16* a16   = (_Float16*)alloc((size_t)2 * 4194304 * 2);     // q16|k16 inputs
    float*    vbuf  = (float*)alloc((size_t)4096 * 64 * 4);
    _Float16* vT    = (_Float16*)alloc((size_t)4 * 64 * 1024 * 2);   // per-b [e][t]
    float*    ctx   = (float*)alloc((size_t)4096 * 64 * 4);
    float*    mbuf  = (float*)alloc((size_t)65536 * 4);
    float*    ilbuf = (float*)alloc((size_t)65536 * 4);
    (void)ws_size; (void)in_sizes; (void)n_in; (void)out_size;

    _Float16* qall = qkall;
    _Float16* kall = qkall + (long)4194304;

    // weight transposes/conversions + activation fp16 convert
    transpose_to_f16<<<dim3(2, 32, 16), 256, 0, stream>>>(Wq, WqkT, 1024, 64, 65536, 65536);
    transpose_to_f16<<<dim3(2, 32, 16), 256, 0, stream>>>(Wk, WqkT + (long)1024 * 1024, 1024, 64, 65536, 65536);
    transpose_to_f16<<<dim3(2, 32, 1),  256, 0, stream>>>(Wv, WvT, 1024, 64, 0, 0);
    transpose_to_f16<<<dim3(32, 2, 1),  256, 0, stream>>>(Wo, WoT, 64, 1024, 0, 0);
    cvt_qk_f16<<<dim3(2048, 2, 1), 256, 0, stream>>>(queries, keys, a16);

    // fused q+k projection: glds counted-vmcnt pipeline
    gemm_qk_glds<<<dim3(8, 32, 2), 256, 0, stream>>>(
        a16, WqkT, bq, bk, qkall);

    // v projection: split-K x8 atomic into vbuf (zeroed) -> 256 blocks
    hipMemsetAsync(vbuf, 0, (size_t)4096 * 64 * 4, stream);
    gemm_f16_v2<<<dim3(1, 32, 8), 256, 0, stream>>>(
        values, nullptr, WvT, bv, nullptr, vbuf,
        64, 1024, 1024, 64,
        0, 0, 0,
        /*c_half=*/0, /*atomic=*/1, /*nks=*/8, /*kchunk=*/128);

    // vT per batch: [1024][64] -> [64][1024] fp16
    transpose_to_f16<<<dim3(2, 32, 4), 256, 0, stream>>>(vbuf, vT, 1024, 64, 65536, 65536);

    // softmax stats, then head-mean probabilities + fused PV into ctx
    hipMemsetAsync(ctx, 0, (size_t)4096 * 64 * 4, stream);
    attn_stats<<<dim3(16, 16, 4), 256, 0, stream>>>(qall, kall, mbuf, ilbuf);
    attn_pmean<<<dim3(16, 16, 4), 256, 0, stream>>>(qall, kall, mbuf, ilbuf, vT, attn_ptr, ctx);

    // out = ctx @ Wo + bo (K=64: single iteration)
    gemm_f16_v2<<<dim3(8, 32, 1), 256, 0, stream>>>(
        ctx, nullptr, WoT, bo, nullptr, out_ptr,
        1024, 64, 64, 1024,
        0, 0, 0,
        /*c_half=*/0, /*atomic=*/0, /*nks=*/1, /*kchunk=*/64);
}

// Round 6
// 235.480 us; speedup vs baseline: 1.0913x; 1.0255x over previous
//
#include <hip/hip_runtime.h>
#include <hip/hip_bf16.h>
#include <stdint.h>

typedef _Float16 half8 __attribute__((ext_vector_type(8)));
typedef _Float16 half4 __attribute__((ext_vector_type(4)));
typedef float    f32x4 __attribute__((ext_vector_type(4)));

#define MFMA16(a, b, c) __builtin_amdgcn_mfma_f32_16x16x32_f16(a, b, c, 0, 0, 0)

// global_load_lds helper: 16B per lane, LDS dest = wave-uniform base + lane*16.
typedef __attribute__((address_space(1))) const void GVOID;
typedef __attribute__((address_space(3))) void LVOID;
__device__ __forceinline__ void glds16(const void* g, void* l)
{
    __builtin_amdgcn_global_load_lds((GVOID*)g, (LVOID*)l, 16, 0, 0);
}

// raw barrier with compiler memory fences
#define BARRIER() do { asm volatile("" ::: "memory"); \
    __builtin_amdgcn_s_barrier(); \
    asm volatile("" ::: "memory"); } while (0)

// ---------------------------------------------------------------------------
// PREP megakernel (R6): replaces 4 transpose launches + cvt launch + 3
// zero-fills (vbuf, ctx, full attn incl. the upper-triangle zeros that
// attn_pmean's trivial blocks used to write). 13 enqueued ops -> 7; the
// serialized launch tails were the largest unexplained pool (R5 accounting).
// Flat block-id ranges:
//   [0,2048)      WqT/WkT transpose  (R=1024,C=64, 16 heads each)
//   [2048,2112)   WvT transpose      (R=1024,C=64)
//   [2112,2176)   WoT transpose      (R=64,C=1024)
//   [2176,6272)   q/k fp32->fp16 convert (2048 blocks each)
//   [6272,6528)   zero vbuf (1 MB)
//   [6528,6784)   zero ctx  (1 MB)
//   [6784,10880)  zero attn (16.8 MB)
// ---------------------------------------------------------------------------
__global__ __launch_bounds__(256) void prep_all(
    const float* __restrict__ Wq, const float* __restrict__ Wk,
    const float* __restrict__ Wv, const float* __restrict__ Wo,
    const float* __restrict__ queries, const float* __restrict__ keys,
    _Float16* __restrict__ WqkT, _Float16* __restrict__ WvT,
    _Float16* __restrict__ WoT, _Float16* __restrict__ a16,
    float* __restrict__ vbuf, float* __restrict__ ctx,
    float* __restrict__ attn)
{
    __shared__ float t[32][33];
    const int id = blockIdx.x;
    const int tid = threadIdx.x;

    if (id < 2176) {
        // ---- 32x32 fp32->fp16 transposes ----
        const float* X; _Float16* Y; int R, C, bx, by;
        if (id < 2048) {                    // Wq / Wk per-head [1024][64]
            const int isK = id >> 10;
            const int local = id & 1023;
            bx = local & 1;
            by = (local >> 1) & 31;
            const int hz = local >> 6;
            X = (isK ? Wk : Wq) + (long)hz * 65536;
            Y = WqkT + (long)isK * 1048576 + (long)hz * 65536;
            R = 1024; C = 64;
        } else if (id < 2112) {             // Wv [1024][64]
            const int local = id - 2048;
            bx = local & 1; by = local >> 1;
            X = Wv; Y = WvT; R = 1024; C = 64;
        } else {                            // Wo [64][1024]
            const int local = id - 2112;
            bx = local & 31; by = local >> 5;
            X = Wo; Y = WoT; R = 64; C = 1024;
        }
        const int c0 = bx * 32, r0 = by * 32;
        const int tx = tid & 31, ty = tid >> 5;
#pragma unroll
        for (int i = 0; i < 4; ++i)
            t[ty + i * 8][tx] = X[(long)(r0 + ty + i * 8) * C + c0 + tx];
        __syncthreads();
#pragma unroll
        for (int i = 0; i < 4; ++i)
            Y[(long)(c0 + ty + i * 8) * R + r0 + tx] = (_Float16)t[tx][ty + i * 8];
    } else if (id < 6272) {
        // ---- q/k fp32 -> fp16 convert ----
        const int isK = (id - 2176) >> 11;
        const int local = (id - 2176) & 2047;
        const float* S = isK ? keys : queries;
        _Float16* Dz = a16 + (long)isK * 4194304;
        const long i = ((long)local * 256 + tid) * 8;
        const float4 v0 = *(const float4*)(S + i);
        const float4 v1 = *(const float4*)(S + i + 4);
        half8 h;
        h[0] = (_Float16)v0.x; h[1] = (_Float16)v0.y;
        h[2] = (_Float16)v0.z; h[3] = (_Float16)v0.w;
        h[4] = (_Float16)v1.x; h[5] = (_Float16)v1.y;
        h[6] = (_Float16)v1.z; h[7] = (_Float16)v1.w;
        *(half8*)(Dz + i) = h;
    } else if (id < 6528) {
        const float4 z = {0.f, 0.f, 0.f, 0.f};
        ((float4*)vbuf)[(long)(id - 6272) * 256 + tid] = z;
    } else if (id < 6784) {
        const float4 z = {0.f, 0.f, 0.f, 0.f};
        ((float4*)ctx)[(long)(id - 6528) * 256 + tid] = z;
    } else {
        const float4 z = {0.f, 0.f, 0.f, 0.f};
        ((float4*)attn)[(long)(id - 6784) * 256 + tid] = z;
    }
}

// ---------------------------------------------------------------------------
// fp32->fp16 transpose (kept for vT: depends on vproj output).
// ---------------------------------------------------------------------------
__global__ __launch_bounds__(256) void transpose_to_f16(
    const float* __restrict__ X, _Float16* __restrict__ Y,
    int R, int C, long inBS, long outBS)
{
    __shared__ float t[32][33];
    const int bz = blockIdx.z;
    X += (long)bz * inBS;
    Y += (long)bz * outBS;
    const int c0 = blockIdx.x * 32, r0 = blockIdx.y * 32;
    const int tx = threadIdx.x & 31, ty = threadIdx.x >> 5;
#pragma unroll
    for (int i = 0; i < 4; ++i)
        t[ty + i * 8][tx] = X[(long)(r0 + ty + i * 8) * C + c0 + tx];
    __syncthreads();
#pragma unroll
    for (int i = 0; i < 4; ++i)
        Y[(long)(c0 + ty + i * 8) * R + r0 + tx] = (_Float16)t[tx][ty + i * 8];
}

// ---------------------------------------------------------------------------
// q+k projection GEMM: glds + counted-vmcnt 2-buffer pipeline (R5-passing).
// ---------------------------------------------------------------------------
__global__ __launch_bounds__(256, 2) void gemm_qk_glds(
    const _Float16* __restrict__ A16,
    const _Float16* __restrict__ BT,
    const float* __restrict__ bias0, const float* __restrict__ bias1,
    _Float16* __restrict__ Cout)
{
    __shared__ __align__(16) _Float16 As[2][128 * 64];
    __shared__ __align__(16) _Float16 Bs[2][128 * 64];

    const int gx  = gridDim.x, gy = gridDim.y;
    const int nwg = gx * gy * (int)gridDim.z;
    const int lid = (int)blockIdx.x + gx * ((int)blockIdx.y + gy * (int)blockIdx.z);
    const int q8  = nwg >> 3;
    const int xcd = lid & 7, loc = lid >> 3;
    const int sw  = xcd * q8 + loc;
    const int nt  = sw % gx;
    const int tm2 = sw / gx;
    const int mt  = tm2 % gy;
    const int z   = tm2 / gy;

    const int n0 = nt * 128;
    const int m0 = mt * 128;
    const int tid  = threadIdx.x;
    const int wave = tid >> 6, lane = tid & 63;
    const int m16  = lane & 15, quad = lane >> 4;

    const char* Az = (const char*)(A16 + (long)z * 4194304);
    const char* Bz = (const char*)(BT  + (long)z * 1048576);

    const int colbyte = (((lane & 7) ^ (lane >> 3)) << 4);
    const char* gaBase = Az + ((long)(m0 + wave * 32 + (lane >> 3)) << 11) + colbyte;
    const char* gbBase = Bz + ((long)(n0 + wave * 32 + (lane >> 3)) << 11) + colbyte;

    f32x4 acc[2][8];
    {
        f32x4 zz = {0.f, 0.f, 0.f, 0.f};
#pragma unroll
        for (int i = 0; i < 2; ++i)
#pragma unroll
            for (int j = 0; j < 8; ++j) acc[i][j] = zz;
    }

    auto STAGE = [&](int bf, int k0) {
        const char* ga = gaBase + (k0 << 1);
        const char* gb = gbBase + (k0 << 1);
        _Float16* la = &As[bf][wave * 32 * 64];
        _Float16* lb = &Bs[bf][wave * 32 * 64];
#pragma unroll
        for (int i = 0; i < 4; ++i) {
            glds16(ga + (long)i * 8 * 2048, la + i * 8 * 64);
            glds16(gb + (long)i * 8 * 2048, lb + i * 8 * 64);
        }
    };

    auto COMPUTE = [&](int bf) {
        const char* Ab = (const char*)&As[bf][0];
        const char* Bp = (const char*)&Bs[bf][0];
        const int sw4 = (m16 & 7) << 4;
#pragma unroll
        for (int kss = 0; kss < 2; ++kss) {
            const int kbs = (kss * 64 + quad * 16) ^ sw4;
            const half8 a0 = *(const half8*)(Ab + (wave * 32 + m16) * 128 + kbs);
            const half8 a1 = *(const half8*)(Ab + (wave * 32 + 16 + m16) * 128 + kbs);
#pragma unroll
            for (int c = 0; c < 8; ++c) {
                const half8 bfr = *(const half8*)(Bp + (c * 16 + m16) * 128 + kbs);
                acc[0][c] = MFMA16(a0, bfr, acc[0][c]);
                acc[1][c] = MFMA16(a1, bfr, acc[1][c]);
            }
        }
    };

    STAGE(0, 0);
    STAGE(1, 64);
    int cur = 0;
    for (int t = 0; t < 15; ++t) {
        asm volatile("s_waitcnt vmcnt(8)" ::: "memory");
        __builtin_amdgcn_sched_barrier(0);
        BARRIER();
        COMPUTE(cur);
        BARRIER();
        if (t < 14) STAGE(cur, (t + 2) * 64);
        cur ^= 1;
    }
    asm volatile("s_waitcnt vmcnt(0)" ::: "memory");
    __builtin_amdgcn_sched_barrier(0);
    BARRIER();
    COMPUTE(cur);

    const float* bias = z ? bias1 : bias0;
    _Float16* Cz = Cout + (long)z * 4194304;
#pragma unroll
    for (int hh = 0; hh < 2; ++hh) {
#pragma unroll
        for (int c = 0; c < 8; ++c) {
            const int col = n0 + c * 16 + m16;
            const float bb = bias[col];
#pragma unroll
            for (int r = 0; r < 4; ++r) {
                const int row = m0 + wave * 32 + hh * 16 + quad * 4 + r;
                Cz[(long)row * 1024 + col] = (_Float16)(acc[hh][c][r] + bb);
            }
        }
    }
}

// ---------------------------------------------------------------------------
// MFMA GEMM (fp32 A path) — v-proj / out (unchanged).
// ---------------------------------------------------------------------------
__global__ __launch_bounds__(256, 2) void gemm_f16_v2(
    const float* __restrict__ A0, const float* __restrict__ A1,
    const _Float16* __restrict__ BT,
    const float* __restrict__ bias0, const float* __restrict__ bias1,
    void* __restrict__ Cout,
    int N, int lda, int ldbt, int ldc,
    long aBS, long bBS, long cBS,
    int c_half, int atomic, int nks, int kchunk)
{
    __shared__ __align__(16) _Float16 As[128][72];
    __shared__ __align__(16) _Float16 Bs[128][72];

    const int gx  = gridDim.x, gy = gridDim.y;
    const int nwg = gx * gy * (int)gridDim.z;
    const int lid = (int)blockIdx.x + gx * ((int)blockIdx.y + gy * (int)blockIdx.z);
    const int q8  = nwg >> 3, r8 = nwg & 7;
    const int xcd = lid & 7, loc = lid >> 3;
    const int sw  = (xcd < r8 ? xcd * (q8 + 1) : r8 * (q8 + 1) + (xcd - r8) * q8) + loc;
    const int nt  = sw % gx;
    const int tm2 = sw / gx;
    const int mt  = tm2 % gy;
    const int bz  = tm2 / gy;

    const int b = bz / nks, ks = bz % nks;
    const int kbeg = ks * kchunk;
    const int kend = kbeg + kchunk;

    const float* A = A1 ? (b ? A1 : A0) : (A0 + (long)b * aBS);
    const _Float16* Bb = BT + (long)b * bBS;

    const int n0 = nt * 128;
    const int m0 = mt * 128;
    const int tid  = threadIdx.x;
    const int wave = tid >> 6, lane = tid & 63;
    const int m16  = lane & 15, quad = lane >> 4;

    const int acol = (tid & 15) * 4;
    const int arb  = tid >> 4;
    const int bj   = tid >> 1;
    const int bcc  = (tid & 1) * 32;
    int jn = n0 + bj; if (jn > N - 1) jn = N - 1;
    const _Float16* bpB = Bb + (long)jn * ldbt;

    f32x4 acc[2][8];
    {
        f32x4 zz = {0.f, 0.f, 0.f, 0.f};
#pragma unroll
        for (int i = 0; i < 2; ++i)
#pragma unroll
            for (int j = 0; j < 8; ++j) acc[i][j] = zz;
    }

    for (int k0 = kbeg; k0 < kend; k0 += 64) {
        {
            float4 av[8];
#pragma unroll
            for (int p = 0; p < 8; ++p)
                av[p] = *(const float4*)(A + (long)(m0 + arb + p * 16) * lda + k0 + acol);
#pragma unroll
            for (int p = 0; p < 8; ++p) {
                half4 hv;
                hv[0] = (_Float16)av[p].x; hv[1] = (_Float16)av[p].y;
                hv[2] = (_Float16)av[p].z; hv[3] = (_Float16)av[p].w;
                *(half4*)&As[arb + p * 16][acol] = hv;
            }
        }
        {
            const _Float16* bp = bpB + k0 + bcc;
            half8 b0 = *(const half8*)(bp);
            half8 b1 = *(const half8*)(bp + 8);
            half8 b2 = *(const half8*)(bp + 16);
            half8 b3 = *(const half8*)(bp + 24);
            *(half8*)&Bs[bj][bcc]      = b0;
            *(half8*)&Bs[bj][bcc + 8]  = b1;
            *(half8*)&Bs[bj][bcc + 16] = b2;
            *(half8*)&Bs[bj][bcc + 24] = b3;
        }
        __syncthreads();
#pragma unroll
        for (int kss = 0; kss < 2; ++kss) {
            const int ko = kss * 32 + quad * 8;
            const half8 a0 = *(const half8*)&As[wave * 32 + m16][ko];
            const half8 a1 = *(const half8*)&As[wave * 32 + 16 + m16][ko];
#pragma unroll
            for (int c = 0; c < 8; ++c) {
                const half8 bf = *(const half8*)&Bs[c * 16 + m16][ko];
                acc[0][c] = MFMA16(a0, bf, acc[0][c]);
                acc[1][c] = MFMA16(a1, bf, acc[1][c]);
            }
        }
        __syncthreads();
    }

    const float* bias = b ? bias1 : bias0;
    const int addb = (bias != nullptr) && (kbeg == 0);
#pragma unroll
    for (int hh = 0; hh < 2; ++hh) {
#pragma unroll
        for (int c = 0; c < 8; ++c) {
            const int col = n0 + c * 16 + m16;
            if (col >= N) continue;
            const float bb = addb ? bias[col] : 0.f;
#pragma unroll
            for (int r = 0; r < 4; ++r) {
                const int row = m0 + wave * 32 + hh * 16 + quad * 4 + r;
                const float v = acc[hh][c][r] + bb;
                const long idx = (long)b * cBS + (long)row * ldc + col;
                if (atomic)      atomicAdd(&((float*)Cout)[idx], v);
                else if (c_half) ((_Float16*)Cout)[idx] = (_Float16)v;
                else             ((float*)Cout)[idx] = v;
            }
        }
    }
}

// ---------------------------------------------------------------------------
// Pass 1 R6: per (b,h,s) row stats with KVBLK=128 (two k-tiles per barrier
// pair). Per-block barrier count halves (avg 17 -> 9); compute per stage
// doubles, amortizing the exposed stage latency R5 proved un-pipelinable
// at net-zero cost. LDS 27.6 KB -> still 4 blocks/CU.
// Chunk ch covers tiles 2ch, 2ch+1 (second only if <= st); mask applies
// only to tile == st.
// ---------------------------------------------------------------------------
__global__ __launch_bounds__(256, 4) void attn_stats(
    const _Float16* __restrict__ q_all, const _Float16* __restrict__ k_all,
    float* __restrict__ m_out, float* __restrict__ il_out)
{
    const int st = blockIdx.x, h = blockIdx.y, b = blockIdx.z;
    const int tid = threadIdx.x, wave = tid >> 6, lane = tid & 63;
    const int m16 = lane & 15, quad = lane >> 4;
    const int s0 = st * 64;
    const int sw = s0 + wave * 16;

    __shared__ __align__(16) _Float16 qs[64][72];
    __shared__ __align__(16) _Float16 ks[128][72];

    const int srow = tid >> 2;              // 0..63
    const int scol = (tid & 3) * 16;        // 0,16,32,48

    {
        const _Float16* qsrc = q_all + ((long)(b * 1024 + s0 + srow)) * 1024 + h * 64 + scol;
        *(half8*)&qs[srow][scol]     = *(const half8*)(qsrc);
        *(half8*)&qs[srow][scol + 8] = *(const half8*)(qsrc + 8);
    }

    const _Float16* ksrcb = k_all + ((long)(b * 1024 + srow)) * 1024 + h * 64 + scol;

    float mr[4], lr[4];
#pragma unroll
    for (int r = 0; r < 4; ++r) { mr[r] = -3.0e38f; lr[r] = 0.f; }

    half8 a0, a1;
    for (int ch = 0; 2 * ch <= st; ++ch) {
        const int tbase = 2 * ch;
        const int two = (tbase + 1 <= st);

        // issue loads early (latency overlaps previous chunk's compute)
        const _Float16* ksrc0 = ksrcb + (long)(tbase * 64) * 1024;
        const half8 k0 = *(const half8*)(ksrc0);
        const half8 k1 = *(const half8*)(ksrc0 + 8);
        half8 k2, k3;
        if (two) {
            const _Float16* ksrc1 = ksrc0 + (long)64 * 1024;
            k2 = *(const half8*)(ksrc1);
            k3 = *(const half8*)(ksrc1 + 8);
        }

        __syncthreads();
        *(half8*)&ks[srow][scol]     = k0;
        *(half8*)&ks[srow][scol + 8] = k1;
        if (two) {
            *(half8*)&ks[64 + srow][scol]     = k2;
            *(half8*)&ks[64 + srow][scol + 8] = k3;
        }
        __syncthreads();

        if (ch == 0) {
            a0 = *(const half8*)&qs[wave * 16 + m16][quad * 8];
            a1 = *(const half8*)&qs[wave * 16 + m16][quad * 8 + 32];
        }

        const int ncol = two ? 8 : 4;
        for (int c = 0; c < ncol; ++c) {
            const half8 b0 = *(const half8*)&ks[c * 16 + m16][quad * 8];
            const half8 b1 = *(const half8*)&ks[c * 16 + m16][quad * 8 + 32];
            f32x4 cc = {0.f, 0.f, 0.f, 0.f};
            cc = MFMA16(a0, b0, cc);
            cc = MFMA16(a1, b1, cc);
            const int tile = tbase + (c >> 2);
            if (tile < st) {
#pragma unroll
                for (int r = 0; r < 4; ++r) {
                    const float zz = cc[r] * 0.125f;
                    const float nm = fmaxf(mr[r], zz);
                    lr[r] = lr[r] * __expf(mr[r] - nm) + __expf(zz - nm);
                    mr[r] = nm;
                }
            } else {
                const int col = tile * 64 + (c & 3) * 16 + m16;
#pragma unroll
                for (int r = 0; r < 4; ++r) {
                    const int row = sw + quad * 4 + r;
                    if (col <= row) {
                        const float zz = cc[r] * 0.125f;
                        const float nm = fmaxf(mr[r], zz);
                        lr[r] = lr[r] * __expf(mr[r] - nm) + __expf(zz - nm);
                        mr[r] = nm;
                    }
                }
            }
        }
    }

#pragma unroll
    for (int mk = 1; mk < 16; mk <<= 1) {
#pragma unroll
        for (int r = 0; r < 4; ++r) {
            const float om = __shfl_xor(mr[r], mk);
            const float ol = __shfl_xor(lr[r], mk);
            const float nm = fmaxf(mr[r], om);
            lr[r] = lr[r] * __expf(mr[r] - nm) + ol * __expf(om - nm);
            mr[r] = nm;
        }
    }
    if (m16 == 0) {
#pragma unroll
        for (int r = 0; r < 4; ++r) {
            const long idx = ((long)(b * 16 + h)) * 1024 + sw + quad * 4 + r;
            m_out[idx]  = mr[r];
            il_out[idx] = 1.f / lr[r];
        }
    }
}

// ---------------------------------------------------------------------------
// Pass 2: head-mean softmax + fused PV (R5-passing body; the zero-fill path
// is gone -- prep_all zeroes attn, trivial blocks just return).
// ---------------------------------------------------------------------------
__global__ __launch_bounds__(256, 3) void attn_pmean(
    const _Float16* __restrict__ q_all, const _Float16* __restrict__ k_all,
    const float* __restrict__ m_in, const float* __restrict__ il_in,
    const _Float16* __restrict__ vT,
    float* __restrict__ attn,
    float* __restrict__ ctx)
{
    const int ttile = blockIdx.x, stile = blockIdx.y, b = blockIdx.z;
    const int tid = threadIdx.x;
    if (ttile > stile) return;

    __shared__ __align__(16) _Float16 qs2[2][64 * 64];
    __shared__ __align__(16) _Float16 ks2[2][64 * 64];
    __shared__ __align__(16) _Float16 ps[64][72];
    __shared__ __align__(16) float mls[16][64];
    __shared__ __align__(16) float ils[16][64];

    const int wave = tid >> 6, lane = tid & 63;
    const int m16 = lane & 15, quad = lane >> 4;
    const int s0 = stile * 64;
    const int t0 = ttile * 64;
    const int sw = s0 + wave * 16;
    const int diag = (ttile == stile);

    {
        const int hh = tid >> 4;
        const int c4 = (tid & 15) * 4;
        const long ix = ((long)(b * 16 + hh)) * 1024 + s0 + c4;
        const float4 mv4 = *(const float4*)&m_in[ix];
        const float4 iv4 = *(const float4*)&il_in[ix];
        *(float4*)&mls[hh][c4] = mv4;
        *(float4*)&ils[hh][c4] = iv4;
    }

    const int colb = (((lane & 7) ^ (lane >> 3)) << 4);
    const char* gq = (const char*)q_all + ((long)(b * 1024 + s0 + wave * 16 + (lane >> 3)) << 11) + colb;
    const char* gk = (const char*)k_all + ((long)(b * 1024 + t0 + wave * 16 + (lane >> 3)) << 11) + colb;

    auto STAGE_P = [&](int bf, int h) {
        const char* q = gq + h * 128;
        const char* k = gk + h * 128;
        _Float16* lq = &qs2[bf][wave * 16 * 64];
        _Float16* lk = &ks2[bf][wave * 16 * 64];
        glds16(q, lq);
        glds16(q + 8 * 2048, lq + 8 * 64);
        glds16(k, lk);
        glds16(k + 8 * 2048, lk + 8 * 64);
    };

    STAGE_P(0, 0);
    STAGE_P(1, 1);
    asm volatile("s_waitcnt lgkmcnt(0)" ::: "memory");
    BARRIER();

    float pm[4][4];
#pragma unroll
    for (int c = 0; c < 4; ++c)
#pragma unroll
        for (int r = 0; r < 4; ++r) pm[c][r] = 0.f;

    const int swz = (m16 & 7) << 4;
    int cur = 0;

    auto COMPUTE_H = [&](int h, int bf) {
        const char* Qc = (const char*)&qs2[bf][0];
        const char* Kc = (const char*)&ks2[bf][0];
        const half8 a0 = *(const half8*)(Qc + (wave * 16 + m16) * 128 + ((quad * 16) ^ swz));
        const half8 a1 = *(const half8*)(Qc + (wave * 16 + m16) * 128 + ((quad * 16 + 64) ^ swz));
        const float4 mv = *(const float4*)&mls[h][wave * 16 + quad * 4];
        const float4 iv = *(const float4*)&ils[h][wave * 16 + quad * 4];
        const float mrow[4] = {mv.x, mv.y, mv.z, mv.w};
        const float irow[4] = {iv.x, iv.y, iv.z, iv.w};
        if (!diag) {
#pragma unroll
            for (int c = 0; c < 4; ++c) {
                const half8 b0 = *(const half8*)(Kc + (c * 16 + m16) * 128 + ((quad * 16) ^ swz));
                const half8 b1 = *(const half8*)(Kc + (c * 16 + m16) * 128 + ((quad * 16 + 64) ^ swz));
                f32x4 cc = {0.f, 0.f, 0.f, 0.f};
                cc = MFMA16(a0, b0, cc);
                cc = MFMA16(a1, b1, cc);
#pragma unroll
                for (int r = 0; r < 4; ++r)
                    pm[c][r] += __expf(cc[r] * 0.125f - mrow[r]) * irow[r];
            }
        } else {
#pragma unroll
            for (int c = 0; c < 4; ++c) {
                const half8 b0 = *(const half8*)(Kc + (c * 16 + m16) * 128 + ((quad * 16) ^ swz));
                const half8 b1 = *(const half8*)(Kc + (c * 16 + m16) * 128 + ((quad * 16 + 64) ^ swz));
                f32x4 cc = {0.f, 0.f, 0.f, 0.f};
                cc = MFMA16(a0, b0, cc);
                cc = MFMA16(a1, b1, cc);
                const int col = t0 + c * 16 + m16;
#pragma unroll
                for (int r = 0; r < 4; ++r) {
                    const int row = sw + quad * 4 + r;
                    if (col <= row)
                        pm[c][r] += __expf(cc[r] * 0.125f - mrow[r]) * irow[r];
                }
            }
        }
    };

    for (int h = 0; h < 15; ++h) {
        asm volatile("s_waitcnt vmcnt(4)" ::: "memory");
        __builtin_amdgcn_sched_barrier(0);
        BARRIER();
        COMPUTE_H(h, cur);
        BARRIER();
        if (h < 14) STAGE_P(cur, h + 2);
        cur ^= 1;
    }
    asm volatile("s_waitcnt vmcnt(0)" ::: "memory");
    __builtin_amdgcn_sched_barrier(0);
    BARRIER();
    COMPUTE_H(15, cur);

#pragma unroll
    for (int c = 0; c < 4; ++c) {
#pragma unroll
        for (int r = 0; r < 4; ++r) {
            const int rloc = (wave << 4) + (quad << 2) + r;
            const int cloc = c * 16 + m16;
            const float p = pm[c][r] * 0.0625f;
            attn[((long)(b * 1024 + s0 + rloc)) * 1024 + t0 + cloc] = p;
            ps[rloc][cloc] = (_Float16)p;
        }
    }
    __syncthreads();

    const _Float16* vTb = vT + (long)b * 65536 + t0;
    f32x4 apv[4];
    {
        f32x4 zz = {0.f, 0.f, 0.f, 0.f};
#pragma unroll
        for (int c = 0; c < 4; ++c) apv[c] = zz;
    }
#pragma unroll
    for (int kss = 0; kss < 2; ++kss) {
        const half8 a = *(const half8*)&ps[wave * 16 + m16][kss * 32 + quad * 8];
#pragma unroll
        for (int c = 0; c < 4; ++c) {
            const half8 bf = *(const half8*)(vTb + (long)(c * 16 + m16) * 1024 + kss * 32 + quad * 8);
            apv[c] = MFMA16(a, bf, apv[c]);
        }
    }
#pragma unroll
    for (int c = 0; c < 4; ++c) {
#pragma unroll
        for (int r = 0; r < 4; ++r) {
            const int row = sw + quad * 4 + r;
            const int e   = c * 16 + m16;
            atomicAdd(&ctx[((long)(b * 1024 + row)) * 64 + e], apv[c][r]);
        }
    }
}

// ---------------------------------------------------------------------------
extern "C" void kernel_launch(void* const* d_in, const int* in_sizes, int n_in,
                              void* d_out, int out_size, void* d_ws, size_t ws_size,
                              hipStream_t stream)
{
    const float* queries = (const float*)d_in[0];
    const float* keys    = (const float*)d_in[1];
    const float* values  = (const float*)d_in[2];
    const float* Wq = (const float*)d_in[4];
    const float* bq = (const float*)d_in[5];
    const float* Wk = (const float*)d_in[6];
    const float* bk = (const float*)d_in[7];
    const float* Wv = (const float*)d_in[8];
    const float* bv = (const float*)d_in[9];
    const float* Wo = (const float*)d_in[10];
    const float* bo = (const float*)d_in[11];

    float* out_ptr  = (float*)d_out;                   // [4096][1024]
    float* attn_ptr = out_ptr + (long)4096 * 1024;     // [4][1024][1024]

    uint8_t* w = (uint8_t*)d_ws;
    size_t off = 0;
    auto alloc = [&](size_t bytes) {
        void* p = w + off;
        off = (off + bytes + 255) & ~(size_t)255;
        return p;
    };
    _Float16* WqkT  = (_Float16*)alloc((size_t)2 * 1024 * 1024 * 2); // WqT|WkT [n][d]
    _Float16* WvT   = (_Float16*)alloc((size_t)64 * 1024 * 2);       // [e][d]
    _Float16* WoT   = (_Float16*)alloc((size_t)1024 * 64 * 2);       // [d][e]
    _Float16* qkall = (_Float16*)alloc((size_t)2 * 4194304 * 2);     // qall|kall
    _Float16* a16   = (_Float16*)alloc((size_t)2 * 4194304 * 2);     // q16|k16 inputs
    float*    vbuf  = (float*)alloc((size_t)4096 * 64 * 4);
    _Float16* vT    = (_Float16*)alloc((size_t)4 * 64 * 1024 * 2);   // per-b [e][t]
    float*    ctx   = (float*)alloc((size_t)4096 * 64 * 4);
    float*    mbuf  = (float*)alloc((size_t)65536 * 4);
    float*    ilbuf = (float*)alloc((size_t)65536 * 4);
    (void)ws_size; (void)in_sizes; (void)n_in; (void)out_size;

    _Float16* qall = qkall;
    _Float16* kall = qkall + (long)4194304;

    // ONE prep launch: all weight transposes, q/k cvt, and zero-fills
    // (vbuf, ctx, full attn -- incl. the upper triangle pmean used to write)
    prep_all<<<dim3(10880, 1, 1), 256, 0, stream>>>(
        Wq, Wk, Wv, Wo, queries, keys,
        WqkT, WvT, WoT, a16, vbuf, ctx, attn_ptr);

    // fused q+k projection: glds counted-vmcnt pipeline
    gemm_qk_glds<<<dim3(8, 32, 2), 256, 0, stream>>>(
        a16, WqkT, bq, bk, qkall);

    // v projection: split-K x8 atomic into vbuf (zeroed by prep)
    gemm_f16_v2<<<dim3(1, 32, 8), 256, 0, stream>>>(
        values, nullptr, WvT, bv, nullptr, vbuf,
        64, 1024, 1024, 64,
        0, 0, 0,
        /*c_half=*/0, /*atomic=*/1, /*nks=*/8, /*kchunk=*/128);

    // vT per batch: [1024][64] -> [64][1024] fp16
    transpose_to_f16<<<dim3(2, 32, 4), 256, 0, stream>>>(vbuf, vT, 1024, 64, 65536, 65536);

    // softmax stats (KVBLK=128), then head-mean probabilities + fused PV
    attn_stats<<<dim3(16, 16, 4), 256, 0, stream>>>(qall, kall, mbuf, ilbuf);
    attn_pmean<<<dim3(16, 16, 4), 256, 0, stream>>>(qall, kall, mbuf, ilbuf, vT, attn_ptr, ctx);

    // out = ctx @ Wo + bo (K=64: single iteration)
    gemm_f16_v2<<<dim3(8, 32, 1), 256, 0, stream>>>(
        ctx, nullptr, WoT, bo, nullptr, out_ptr,
        1024, 64, 64, 1024,
        0, 0, 0,
        /*c_half=*/0, /*atomic=*/0, /*nks=*/1, /*kchunk=*/64);
}

// Round 7
// 229.784 us; speedup vs baseline: 1.1184x; 1.0248x over previous
//
#include <hip/hip_runtime.h>
#include <hip/hip_bf16.h>
#include <stdint.h>

typedef _Float16 half8 __attribute__((ext_vector_type(8)));
typedef _Float16 half4 __attribute__((ext_vector_type(4)));
typedef float    f32x4 __attribute__((ext_vector_type(4)));

#define MFMA16(a, b, c) __builtin_amdgcn_mfma_f32_16x16x32_f16(a, b, c, 0, 0, 0)

// global_load_lds helper: 16B per lane, LDS dest = wave-uniform base + lane*16.
typedef __attribute__((address_space(1))) const void GVOID;
typedef __attribute__((address_space(3))) void LVOID;
__device__ __forceinline__ void glds16(const void* g, void* l)
{
    __builtin_amdgcn_global_load_lds((GVOID*)g, (LVOID*)l, 16, 0, 0);
}

// raw barrier with compiler memory fences
#define BARRIER() do { asm volatile("" ::: "memory"); \
    __builtin_amdgcn_s_barrier(); \
    asm volatile("" ::: "memory"); } while (0)

// ---------------------------------------------------------------------------
// PREP megakernel: weight transposes + q/k fp16 convert + zero-fills.
// R7: vbuf zero-fill dropped (vproj no longer split-K/atomic).
//   [0,2048)      WqT/WkT transpose
//   [2048,2112)   WvT transpose
//   [2112,2176)   WoT transpose
//   [2176,6272)   q/k fp32->fp16 convert
//   [6272,6528)   zero ctx  (1 MB)
//   [6528,10624)  zero attn (16.8 MB)
// ---------------------------------------------------------------------------
__global__ __launch_bounds__(256) void prep_all(
    const float* __restrict__ Wq, const float* __restrict__ Wk,
    const float* __restrict__ Wv, const float* __restrict__ Wo,
    const float* __restrict__ queries, const float* __restrict__ keys,
    _Float16* __restrict__ WqkT, _Float16* __restrict__ WvT,
    _Float16* __restrict__ WoT, _Float16* __restrict__ a16,
    float* __restrict__ ctx, float* __restrict__ attn)
{
    __shared__ float t[32][33];
    const int id = blockIdx.x;
    const int tid = threadIdx.x;

    if (id < 2176) {
        const float* X; _Float16* Y; int R, C, bx, by;
        if (id < 2048) {
            const int isK = id >> 10;
            const int local = id & 1023;
            bx = local & 1;
            by = (local >> 1) & 31;
            const int hz = local >> 6;
            X = (isK ? Wk : Wq) + (long)hz * 65536;
            Y = WqkT + (long)isK * 1048576 + (long)hz * 65536;
            R = 1024; C = 64;
        } else if (id < 2112) {
            const int local = id - 2048;
            bx = local & 1; by = local >> 1;
            X = Wv; Y = WvT; R = 1024; C = 64;
        } else {
            const int local = id - 2112;
            bx = local & 31; by = local >> 5;
            X = Wo; Y = WoT; R = 64; C = 1024;
        }
        const int c0 = bx * 32, r0 = by * 32;
        const int tx = tid & 31, ty = tid >> 5;
#pragma unroll
        for (int i = 0; i < 4; ++i)
            t[ty + i * 8][tx] = X[(long)(r0 + ty + i * 8) * C + c0 + tx];
        __syncthreads();
#pragma unroll
        for (int i = 0; i < 4; ++i)
            Y[(long)(c0 + ty + i * 8) * R + r0 + tx] = (_Float16)t[tx][ty + i * 8];
    } else if (id < 6272) {
        const int isK = (id - 2176) >> 11;
        const int local = (id - 2176) & 2047;
        const float* S = isK ? keys : queries;
        _Float16* Dz = a16 + (long)isK * 4194304;
        const long i = ((long)local * 256 + tid) * 8;
        const float4 v0 = *(const float4*)(S + i);
        const float4 v1 = *(const float4*)(S + i + 4);
        half8 h;
        h[0] = (_Float16)v0.x; h[1] = (_Float16)v0.y;
        h[2] = (_Float16)v0.z; h[3] = (_Float16)v0.w;
        h[4] = (_Float16)v1.x; h[5] = (_Float16)v1.y;
        h[6] = (_Float16)v1.z; h[7] = (_Float16)v1.w;
        *(half8*)(Dz + i) = h;
    } else if (id < 6528) {
        const float4 z = {0.f, 0.f, 0.f, 0.f};
        ((float4*)ctx)[(long)(id - 6272) * 256 + tid] = z;
    } else {
        const float4 z = {0.f, 0.f, 0.f, 0.f};
        ((float4*)attn)[(long)(id - 6528) * 256 + tid] = z;
    }
}

// ---------------------------------------------------------------------------
// R7 fused launch: blocks [0,32) = v-projection (full-K, no atomics, writes
// vT fp16 TRANSPOSED directly -> kills the vT transpose launch + vbuf);
// blocks [32,544) = q+k projection GEMM (R5/R6-passing counted-vmcnt body).
// vproj has no dependence on qk, so its 32 long-K blocks run in the qk
// grid's shadow instead of serially afterward at 0.1 blocks/CU.
// ---------------------------------------------------------------------------
__global__ __launch_bounds__(256, 2) void qk_vproj(
    const _Float16* __restrict__ A16,   // [2][4096][1024] fp16 (q16|k16)
    const _Float16* __restrict__ BT,    // [2][1024][1024] fp16 (WqT|WkT)
    const float* __restrict__ bias0, const float* __restrict__ bias1,
    _Float16* __restrict__ Cout,        // [2][4096][1024] fp16 (qall|kall)
    const float* __restrict__ values,   // [4096][1024] fp32
    const _Float16* __restrict__ WvT,   // [64][1024] fp16
    const float* __restrict__ bv,       // [64]
    _Float16* __restrict__ vT)          // [4][64][1024] fp16
{
    __shared__ __align__(16) char smem[65536];
    const int lid = blockIdx.x;
    const int tid = threadIdx.x;
    const int wave = tid >> 6, lane = tid & 63;
    const int m16  = lane & 15, quad = lane >> 4;

    if (lid < 32) {
        // ================= v-projection role =================
        // C[4096][64] = values[4096][1024] @ WvT^T, written transposed fp16.
        _Float16 (*As)[72] = (_Float16(*)[72])smem;                  // 128x72
        _Float16 (*Bs)[72] = (_Float16(*)[72])(smem + 128 * 72 * 2); // 128x72
        const int mt = lid;
        const int m0 = mt * 128;

        const int acol = (tid & 15) * 4;
        const int arb  = tid >> 4;
        const int bj   = tid >> 1;
        const int bcc  = (tid & 1) * 32;
        const int jn = (bj > 63) ? 63 : bj;     // N=64 clamp
        const _Float16* bpB = WvT + (long)jn * 1024;

        f32x4 acc[2][8];
        {
            f32x4 zz = {0.f, 0.f, 0.f, 0.f};
#pragma unroll
            for (int i = 0; i < 2; ++i)
#pragma unroll
                for (int j = 0; j < 8; ++j) acc[i][j] = zz;
        }

        for (int k0 = 0; k0 < 1024; k0 += 64) {
            {
                float4 av[8];
#pragma unroll
                for (int p = 0; p < 8; ++p)
                    av[p] = *(const float4*)(values + (long)(m0 + arb + p * 16) * 1024 + k0 + acol);
#pragma unroll
                for (int p = 0; p < 8; ++p) {
                    half4 hv;
                    hv[0] = (_Float16)av[p].x; hv[1] = (_Float16)av[p].y;
                    hv[2] = (_Float16)av[p].z; hv[3] = (_Float16)av[p].w;
                    *(half4*)&As[arb + p * 16][acol] = hv;
                }
            }
            {
                const _Float16* bp = bpB + k0 + bcc;
                half8 b0 = *(const half8*)(bp);
                half8 b1 = *(const half8*)(bp + 8);
                half8 b2 = *(const half8*)(bp + 16);
                half8 b3 = *(const half8*)(bp + 24);
                *(half8*)&Bs[bj][bcc]      = b0;
                *(half8*)&Bs[bj][bcc + 8]  = b1;
                *(half8*)&Bs[bj][bcc + 16] = b2;
                *(half8*)&Bs[bj][bcc + 24] = b3;
            }
            __syncthreads();
#pragma unroll
            for (int kss = 0; kss < 2; ++kss) {
                const int ko = kss * 32 + quad * 8;
                const half8 a0 = *(const half8*)&As[wave * 32 + m16][ko];
                const half8 a1 = *(const half8*)&As[wave * 32 + 16 + m16][ko];
#pragma unroll
                for (int c = 0; c < 4; ++c) {   // only cols < 64 exist
                    const half8 bf = *(const half8*)&Bs[c * 16 + m16][ko];
                    acc[0][c] = MFMA16(a0, bf, acc[0][c]);
                    acc[1][c] = MFMA16(a1, bf, acc[1][c]);
                }
            }
            __syncthreads();
        }

        // epilogue: vT[b][e][t] = (fp16)(acc + bv[e]); b=row>>10, t=row&1023
#pragma unroll
        for (int hh = 0; hh < 2; ++hh) {
#pragma unroll
            for (int c = 0; c < 4; ++c) {
                const int e  = c * 16 + m16;
                const float bb = bv[e];
#pragma unroll
                for (int r = 0; r < 4; ++r) {
                    const int row = m0 + wave * 32 + hh * 16 + quad * 4 + r;
                    const int b = row >> 10, tt = row & 1023;
                    vT[(long)b * 65536 + (long)e * 1024 + tt] =
                        (_Float16)(acc[hh][c][r] + bb);
                }
            }
        }
        return;
    }

    // ================= q+k projection role =================
    const int lid2 = lid - 32;            // 0..511
    const int xcd = lid2 & 7, loc = lid2 >> 3;
    const int sw  = xcd * 64 + loc;       // bijective (512 % 8 == 0)
    const int nt  = sw & 7;
    const int tm2 = sw >> 3;
    const int mt  = tm2 & 31;
    const int z   = tm2 >> 5;             // 0 = q, 1 = k

    const int n0 = nt * 128;
    const int m0 = mt * 128;

    const char* Az = (const char*)(A16 + (long)z * 4194304);
    const char* Bz = (const char*)(BT  + (long)z * 1048576);

    const int colbyte = (((lane & 7) ^ (lane >> 3)) << 4);
    const char* gaBase = Az + ((long)(m0 + wave * 32 + (lane >> 3)) << 11) + colbyte;
    const char* gbBase = Bz + ((long)(n0 + wave * 32 + (lane >> 3)) << 11) + colbyte;

    // LDS: As[2] at 0 / 16384; Bs[2] at 32768 / 49152 (each 128x64 fp16)
    f32x4 acc[2][8];
    {
        f32x4 zz = {0.f, 0.f, 0.f, 0.f};
#pragma unroll
        for (int i = 0; i < 2; ++i)
#pragma unroll
            for (int j = 0; j < 8; ++j) acc[i][j] = zz;
    }

    auto STAGE = [&](int bf, int k0) {
        const char* ga = gaBase + (k0 << 1);
        const char* gb = gbBase + (k0 << 1);
        _Float16* la = (_Float16*)(smem + bf * 16384) + wave * 32 * 64;
        _Float16* lb = (_Float16*)(smem + 32768 + bf * 16384) + wave * 32 * 64;
#pragma unroll
        for (int i = 0; i < 4; ++i) {
            glds16(ga + (long)i * 8 * 2048, la + i * 8 * 64);
            glds16(gb + (long)i * 8 * 2048, lb + i * 8 * 64);
        }
    };

    auto COMPUTE = [&](int bf) {
        const char* Ab = smem + bf * 16384;
        const char* Bp = smem + 32768 + bf * 16384;
        const int sw4 = (m16 & 7) << 4;
#pragma unroll
        for (int kss = 0; kss < 2; ++kss) {
            const int kbs = (kss * 64 + quad * 16) ^ sw4;
            const half8 a0 = *(const half8*)(Ab + (wave * 32 + m16) * 128 + kbs);
            const half8 a1 = *(const half8*)(Ab + (wave * 32 + 16 + m16) * 128 + kbs);
#pragma unroll
            for (int c = 0; c < 8; ++c) {
                const half8 bfr = *(const half8*)(Bp + (c * 16 + m16) * 128 + kbs);
                acc[0][c] = MFMA16(a0, bfr, acc[0][c]);
                acc[1][c] = MFMA16(a1, bfr, acc[1][c]);
            }
        }
    };

    STAGE(0, 0);
    STAGE(1, 64);
    int cur = 0;
    for (int t = 0; t < 15; ++t) {
        asm volatile("s_waitcnt vmcnt(8)" ::: "memory");
        __builtin_amdgcn_sched_barrier(0);
        BARRIER();
        COMPUTE(cur);
        BARRIER();
        if (t < 14) STAGE(cur, (t + 2) * 64);
        cur ^= 1;
    }
    asm volatile("s_waitcnt vmcnt(0)" ::: "memory");
    __builtin_amdgcn_sched_barrier(0);
    BARRIER();
    COMPUTE(cur);

    const float* bias = z ? bias1 : bias0;
    _Float16* Cz = Cout + (long)z * 4194304;
#pragma unroll
    for (int hh = 0; hh < 2; ++hh) {
#pragma unroll
        for (int c = 0; c < 8; ++c) {
            const int col = n0 + c * 16 + m16;
            const float bb = bias[col];
#pragma unroll
            for (int r = 0; r < 4; ++r) {
                const int row = m0 + wave * 32 + hh * 16 + quad * 4 + r;
                Cz[(long)row * 1024 + col] = (_Float16)(acc[hh][c][r] + bb);
            }
        }
    }
}

// ---------------------------------------------------------------------------
// MFMA GEMM (fp32 A path) — used only for the out-projection now.
// ---------------------------------------------------------------------------
__global__ __launch_bounds__(256, 2) void gemm_f16_v2(
    const float* __restrict__ A0, const float* __restrict__ A1,
    const _Float16* __restrict__ BT,
    const float* __restrict__ bias0, const float* __restrict__ bias1,
    void* __restrict__ Cout,
    int N, int lda, int ldbt, int ldc,
    long aBS, long bBS, long cBS,
    int c_half, int atomic, int nks, int kchunk)
{
    __shared__ __align__(16) _Float16 As[128][72];
    __shared__ __align__(16) _Float16 Bs[128][72];

    const int gx  = gridDim.x, gy = gridDim.y;
    const int nwg = gx * gy * (int)gridDim.z;
    const int lid = (int)blockIdx.x + gx * ((int)blockIdx.y + gy * (int)blockIdx.z);
    const int q8  = nwg >> 3, r8 = nwg & 7;
    const int xcd = lid & 7, loc = lid >> 3;
    const int sw  = (xcd < r8 ? xcd * (q8 + 1) : r8 * (q8 + 1) + (xcd - r8) * q8) + loc;
    const int nt  = sw % gx;
    const int tm2 = sw / gx;
    const int mt  = tm2 % gy;
    const int bz  = tm2 / gy;

    const int b = bz / nks, ks = bz % nks;
    const int kbeg = ks * kchunk;
    const int kend = kbeg + kchunk;

    const float* A = A1 ? (b ? A1 : A0) : (A0 + (long)b * aBS);
    const _Float16* Bb = BT + (long)b * bBS;

    const int n0 = nt * 128;
    const int m0 = mt * 128;
    const int tid  = threadIdx.x;
    const int wave = tid >> 6, lane = tid & 63;
    const int m16  = lane & 15, quad = lane >> 4;

    const int acol = (tid & 15) * 4;
    const int arb  = tid >> 4;
    const int bj   = tid >> 1;
    const int bcc  = (tid & 1) * 32;
    int jn = n0 + bj; if (jn > N - 1) jn = N - 1;
    const _Float16* bpB = Bb + (long)jn * ldbt;

    f32x4 acc[2][8];
    {
        f32x4 zz = {0.f, 0.f, 0.f, 0.f};
#pragma unroll
        for (int i = 0; i < 2; ++i)
#pragma unroll
            for (int j = 0; j < 8; ++j) acc[i][j] = zz;
    }

    for (int k0 = kbeg; k0 < kend; k0 += 64) {
        {
            float4 av[8];
#pragma unroll
            for (int p = 0; p < 8; ++p)
                av[p] = *(const float4*)(A + (long)(m0 + arb + p * 16) * lda + k0 + acol);
#pragma unroll
            for (int p = 0; p < 8; ++p) {
                half4 hv;
                hv[0] = (_Float16)av[p].x; hv[1] = (_Float16)av[p].y;
                hv[2] = (_Float16)av[p].z; hv[3] = (_Float16)av[p].w;
                *(half4*)&As[arb + p * 16][acol] = hv;
            }
        }
        {
            const _Float16* bp = bpB + k0 + bcc;
            half8 b0 = *(const half8*)(bp);
            half8 b1 = *(const half8*)(bp + 8);
            half8 b2 = *(const half8*)(bp + 16);
            half8 b3 = *(const half8*)(bp + 24);
            *(half8*)&Bs[bj][bcc]      = b0;
            *(half8*)&Bs[bj][bcc + 8]  = b1;
            *(half8*)&Bs[bj][bcc + 16] = b2;
            *(half8*)&Bs[bj][bcc + 24] = b3;
        }
        __syncthreads();
#pragma unroll
        for (int kss = 0; kss < 2; ++kss) {
            const int ko = kss * 32 + quad * 8;
            const half8 a0 = *(const half8*)&As[wave * 32 + m16][ko];
            const half8 a1 = *(const half8*)&As[wave * 32 + 16 + m16][ko];
#pragma unroll
            for (int c = 0; c < 8; ++c) {
                const half8 bf = *(const half8*)&Bs[c * 16 + m16][ko];
                acc[0][c] = MFMA16(a0, bf, acc[0][c]);
                acc[1][c] = MFMA16(a1, bf, acc[1][c]);
            }
        }
        __syncthreads();
    }

    const float* bias = b ? bias1 : bias0;
    const int addb = (bias != nullptr) && (kbeg == 0);
#pragma unroll
    for (int hh = 0; hh < 2; ++hh) {
#pragma unroll
        for (int c = 0; c < 8; ++c) {
            const int col = n0 + c * 16 + m16;
            if (col >= N) continue;
            const float bb = addb ? bias[col] : 0.f;
#pragma unroll
            for (int r = 0; r < 4; ++r) {
                const int row = m0 + wave * 32 + hh * 16 + quad * 4 + r;
                const float v = acc[hh][c][r] + bb;
                const long idx = (long)b * cBS + (long)row * ldc + col;
                if (atomic)      atomicAdd(&((float*)Cout)[idx], v);
                else if (c_half) ((_Float16*)Cout)[idx] = (_Float16)v;
                else             ((float*)Cout)[idx] = v;
            }
        }
    }
}

// ---------------------------------------------------------------------------
// Pass 1: per (b,h,s) row stats, KVBLK=128 (R6-passing, unchanged).
// ---------------------------------------------------------------------------
__global__ __launch_bounds__(256, 4) void attn_stats(
    const _Float16* __restrict__ q_all, const _Float16* __restrict__ k_all,
    float* __restrict__ m_out, float* __restrict__ il_out)
{
    const int st = blockIdx.x, h = blockIdx.y, b = blockIdx.z;
    const int tid = threadIdx.x, wave = tid >> 6, lane = tid & 63;
    const int m16 = lane & 15, quad = lane >> 4;
    const int s0 = st * 64;
    const int sw = s0 + wave * 16;

    __shared__ __align__(16) _Float16 qs[64][72];
    __shared__ __align__(16) _Float16 ks[128][72];

    const int srow = tid >> 2;
    const int scol = (tid & 3) * 16;

    {
        const _Float16* qsrc = q_all + ((long)(b * 1024 + s0 + srow)) * 1024 + h * 64 + scol;
        *(half8*)&qs[srow][scol]     = *(const half8*)(qsrc);
        *(half8*)&qs[srow][scol + 8] = *(const half8*)(qsrc + 8);
    }

    const _Float16* ksrcb = k_all + ((long)(b * 1024 + srow)) * 1024 + h * 64 + scol;

    float mr[4], lr[4];
#pragma unroll
    for (int r = 0; r < 4; ++r) { mr[r] = -3.0e38f; lr[r] = 0.f; }

    half8 a0, a1;
    for (int ch = 0; 2 * ch <= st; ++ch) {
        const int tbase = 2 * ch;
        const int two = (tbase + 1 <= st);

        const _Float16* ksrc0 = ksrcb + (long)(tbase * 64) * 1024;
        const half8 k0 = *(const half8*)(ksrc0);
        const half8 k1 = *(const half8*)(ksrc0 + 8);
        half8 k2, k3;
        if (two) {
            const _Float16* ksrc1 = ksrc0 + (long)64 * 1024;
            k2 = *(const half8*)(ksrc1);
            k3 = *(const half8*)(ksrc1 + 8);
        }

        __syncthreads();
        *(half8*)&ks[srow][scol]     = k0;
        *(half8*)&ks[srow][scol + 8] = k1;
        if (two) {
            *(half8*)&ks[64 + srow][scol]     = k2;
            *(half8*)&ks[64 + srow][scol + 8] = k3;
        }
        __syncthreads();

        if (ch == 0) {
            a0 = *(const half8*)&qs[wave * 16 + m16][quad * 8];
            a1 = *(const half8*)&qs[wave * 16 + m16][quad * 8 + 32];
        }

        const int ncol = two ? 8 : 4;
        for (int c = 0; c < ncol; ++c) {
            const half8 b0 = *(const half8*)&ks[c * 16 + m16][quad * 8];
            const half8 b1 = *(const half8*)&ks[c * 16 + m16][quad * 8 + 32];
            f32x4 cc = {0.f, 0.f, 0.f, 0.f};
            cc = MFMA16(a0, b0, cc);
            cc = MFMA16(a1, b1, cc);
            const int tile = tbase + (c >> 2);
            if (tile < st) {
#pragma unroll
                for (int r = 0; r < 4; ++r) {
                    const float zz = cc[r] * 0.125f;
                    const float nm = fmaxf(mr[r], zz);
                    lr[r] = lr[r] * __expf(mr[r] - nm) + __expf(zz - nm);
                    mr[r] = nm;
                }
            } else {
                const int col = tile * 64 + (c & 3) * 16 + m16;
#pragma unroll
                for (int r = 0; r < 4; ++r) {
                    const int row = sw + quad * 4 + r;
                    if (col <= row) {
                        const float zz = cc[r] * 0.125f;
                        const float nm = fmaxf(mr[r], zz);
                        lr[r] = lr[r] * __expf(mr[r] - nm) + __expf(zz - nm);
                        mr[r] = nm;
                    }
                }
            }
        }
    }

#pragma unroll
    for (int mk = 1; mk < 16; mk <<= 1) {
#pragma unroll
        for (int r = 0; r < 4; ++r) {
            const float om = __shfl_xor(mr[r], mk);
            const float ol = __shfl_xor(lr[r], mk);
            const float nm = fmaxf(mr[r], om);
            lr[r] = lr[r] * __expf(mr[r] - nm) + ol * __expf(om - nm);
            mr[r] = nm;
        }
    }
    if (m16 == 0) {
#pragma unroll
        for (int r = 0; r < 4; ++r) {
            const long idx = ((long)(b * 16 + h)) * 1024 + sw + quad * 4 + r;
            m_out[idx]  = mr[r];
            il_out[idx] = 1.f / lr[r];
        }
    }
}

// ---------------------------------------------------------------------------
// Pass 2 R7: head-mean softmax + fused PV. LDS diet: dedicated ps tile gone;
// after the h-loop, P is stashed (chunk-XOR swizzled) into the retired qs2[0]
// buffer. LDS = 16+16+8 = 40 KB exactly -> 4 blocks/CU (was 3).
// ---------------------------------------------------------------------------
__global__ __launch_bounds__(256, 4) void attn_pmean(
    const _Float16* __restrict__ q_all, const _Float16* __restrict__ k_all,
    const float* __restrict__ m_in, const float* __restrict__ il_in,
    const _Float16* __restrict__ vT,
    float* __restrict__ attn,
    float* __restrict__ ctx)
{
    const int ttile = blockIdx.x, stile = blockIdx.y, b = blockIdx.z;
    const int tid = threadIdx.x;
    if (ttile > stile) return;

    __shared__ __align__(16) _Float16 qs2[2][64 * 64];
    __shared__ __align__(16) _Float16 ks2[2][64 * 64];
    __shared__ __align__(16) float mls[16][64];
    __shared__ __align__(16) float ils[16][64];

    const int wave = tid >> 6, lane = tid & 63;
    const int m16 = lane & 15, quad = lane >> 4;
    const int s0 = stile * 64;
    const int t0 = ttile * 64;
    const int sw = s0 + wave * 16;
    const int diag = (ttile == stile);

    {
        const int hh = tid >> 4;
        const int c4 = (tid & 15) * 4;
        const long ix = ((long)(b * 16 + hh)) * 1024 + s0 + c4;
        const float4 mv4 = *(const float4*)&m_in[ix];
        const float4 iv4 = *(const float4*)&il_in[ix];
        *(float4*)&mls[hh][c4] = mv4;
        *(float4*)&ils[hh][c4] = iv4;
    }

    const int colb = (((lane & 7) ^ (lane >> 3)) << 4);
    const char* gq = (const char*)q_all + ((long)(b * 1024 + s0 + wave * 16 + (lane >> 3)) << 11) + colb;
    const char* gk = (const char*)k_all + ((long)(b * 1024 + t0 + wave * 16 + (lane >> 3)) << 11) + colb;

    auto STAGE_P = [&](int bf, int h) {
        const char* q = gq + h * 128;
        const char* k = gk + h * 128;
        _Float16* lq = &qs2[bf][wave * 16 * 64];
        _Float16* lk = &ks2[bf][wave * 16 * 64];
        glds16(q, lq);
        glds16(q + 8 * 2048, lq + 8 * 64);
        glds16(k, lk);
        glds16(k + 8 * 2048, lk + 8 * 64);
    };

    STAGE_P(0, 0);
    STAGE_P(1, 1);
    asm volatile("s_waitcnt lgkmcnt(0)" ::: "memory");
    BARRIER();

    float pm[4][4];
#pragma unroll
    for (int c = 0; c < 4; ++c)
#pragma unroll
        for (int r = 0; r < 4; ++r) pm[c][r] = 0.f;

    const int swz = (m16 & 7) << 4;
    int cur = 0;

    auto COMPUTE_H = [&](int h, int bf) {
        const char* Qc = (const char*)&qs2[bf][0];
        const char* Kc = (const char*)&ks2[bf][0];
        const half8 a0 = *(const half8*)(Qc + (wave * 16 + m16) * 128 + ((quad * 16) ^ swz));
        const half8 a1 = *(const half8*)(Qc + (wave * 16 + m16) * 128 + ((quad * 16 + 64) ^ swz));
        const float4 mv = *(const float4*)&mls[h][wave * 16 + quad * 4];
        const float4 iv = *(const float4*)&ils[h][wave * 16 + quad * 4];
        const float mrow[4] = {mv.x, mv.y, mv.z, mv.w};
        const float irow[4] = {iv.x, iv.y, iv.z, iv.w};
        if (!diag) {
#pragma unroll
            for (int c = 0; c < 4; ++c) {
                const half8 b0 = *(const half8*)(Kc + (c * 16 + m16) * 128 + ((quad * 16) ^ swz));
                const half8 b1 = *(const half8*)(Kc + (c * 16 + m16) * 128 + ((quad * 16 + 64) ^ swz));
                f32x4 cc = {0.f, 0.f, 0.f, 0.f};
                cc = MFMA16(a0, b0, cc);
                cc = MFMA16(a1, b1, cc);
#pragma unroll
                for (int r = 0; r < 4; ++r)
                    pm[c][r] += __expf(cc[r] * 0.125f - mrow[r]) * irow[r];
            }
        } else {
#pragma unroll
            for (int c = 0; c < 4; ++c) {
                const half8 b0 = *(const half8*)(Kc + (c * 16 + m16) * 128 + ((quad * 16) ^ swz));
                const half8 b1 = *(const half8*)(Kc + (c * 16 + m16) * 128 + ((quad * 16 + 64) ^ swz));
                f32x4 cc = {0.f, 0.f, 0.f, 0.f};
                cc = MFMA16(a0, b0, cc);
                cc = MFMA16(a1, b1, cc);
                const int col = t0 + c * 16 + m16;
#pragma unroll
                for (int r = 0; r < 4; ++r) {
                    const int row = sw + quad * 4 + r;
                    if (col <= row)
                        pm[c][r] += __expf(cc[r] * 0.125f - mrow[r]) * irow[r];
                }
            }
        }
    };

    for (int h = 0; h < 15; ++h) {
        asm volatile("s_waitcnt vmcnt(4)" ::: "memory");
        __builtin_amdgcn_sched_barrier(0);
        BARRIER();
        COMPUTE_H(h, cur);
        BARRIER();
        if (h < 14) STAGE_P(cur, h + 2);
        cur ^= 1;
    }
    asm volatile("s_waitcnt vmcnt(0)" ::: "memory");
    __builtin_amdgcn_sched_barrier(0);
    BARRIER();
    COMPUTE_H(15, cur);
    __syncthreads();   // all waves done reading LDS; qs2[0] reusable for P

    // attn write + P stash into qs2[0], chunk-XOR swizzled:
    // byte = rloc*128 + (((cloc>>3) ^ (rloc&7))<<4) + (cloc&7)*2
    {
        char* Pb = (char*)&qs2[0][0];
#pragma unroll
        for (int c = 0; c < 4; ++c) {
#pragma unroll
            for (int r = 0; r < 4; ++r) {
                const int rloc = (wave << 4) + (quad << 2) + r;
                const int cloc = c * 16 + m16;
                const float p = pm[c][r] * 0.0625f;
                attn[((long)(b * 1024 + s0 + rloc)) * 1024 + t0 + cloc] = p;
                const int chunk = (cloc >> 3) ^ (rloc & 7);
                *(_Float16*)(Pb + rloc * 128 + (chunk << 4) + (cloc & 7) * 2) =
                    (_Float16)p;
            }
        }
    }
    __syncthreads();

    // PV: ctx[s][e] += sum_t P[s][t] * vT[e][t]
    const _Float16* vTb = vT + (long)b * 65536 + t0;
    const char* Pb = (const char*)&qs2[0][0];
    const int Rr = wave * 16 + m16;
    f32x4 apv[4];
    {
        f32x4 zz = {0.f, 0.f, 0.f, 0.f};
#pragma unroll
        for (int c = 0; c < 4; ++c) apv[c] = zz;
    }
#pragma unroll
    for (int kss = 0; kss < 2; ++kss) {
        const int chunk = (kss * 4 + quad) ^ (Rr & 7);
        const half8 a = *(const half8*)(Pb + Rr * 128 + (chunk << 4));
#pragma unroll
        for (int c = 0; c < 4; ++c) {
            const half8 bf = *(const half8*)(vTb + (long)(c * 16 + m16) * 1024 + kss * 32 + quad * 8);
            apv[c] = MFMA16(a, bf, apv[c]);
        }
    }
#pragma unroll
    for (int c = 0; c < 4; ++c) {
#pragma unroll
        for (int r = 0; r < 4; ++r) {
            const int row = sw + quad * 4 + r;
            const int e   = c * 16 + m16;
            atomicAdd(&ctx[((long)(b * 1024 + row)) * 64 + e], apv[c][r]);
        }
    }
}

// ---------------------------------------------------------------------------
extern "C" void kernel_launch(void* const* d_in, const int* in_sizes, int n_in,
                              void* d_out, int out_size, void* d_ws, size_t ws_size,
                              hipStream_t stream)
{
    const float* queries = (const float*)d_in[0];
    const float* keys    = (const float*)d_in[1];
    const float* values  = (const float*)d_in[2];
    const float* Wq = (const float*)d_in[4];
    const float* bq = (const float*)d_in[5];
    const float* Wk = (const float*)d_in[6];
    const float* bk = (const float*)d_in[7];
    const float* Wv = (const float*)d_in[8];
    const float* bv = (const float*)d_in[9];
    const float* Wo = (const float*)d_in[10];
    const float* bo = (const float*)d_in[11];

    float* out_ptr  = (float*)d_out;                   // [4096][1024]
    float* attn_ptr = out_ptr + (long)4096 * 1024;     // [4][1024][1024]

    uint8_t* w = (uint8_t*)d_ws;
    size_t off = 0;
    auto alloc = [&](size_t bytes) {
        void* p = w + off;
        off = (off + bytes + 255) & ~(size_t)255;
        return p;
    };
    _Float16* WqkT  = (_Float16*)alloc((size_t)2 * 1024 * 1024 * 2); // WqT|WkT
    _Float16* WvT   = (_Float16*)alloc((size_t)64 * 1024 * 2);       // [e][d]
    _Float16* WoT   = (_Float16*)alloc((size_t)1024 * 64 * 2);       // [d][e]
    _Float16* qkall = (_Float16*)alloc((size_t)2 * 4194304 * 2);     // qall|kall
    _Float16* a16   = (_Float16*)alloc((size_t)2 * 4194304 * 2);     // q16|k16
    _Float16* vT    = (_Float16*)alloc((size_t)4 * 64 * 1024 * 2);   // per-b [e][t]
    float*    ctx   = (float*)alloc((size_t)4096 * 64 * 4);
    float*    mbuf  = (float*)alloc((size_t)65536 * 4);
    float*    ilbuf = (float*)alloc((size_t)65536 * 4);
    (void)ws_size; (void)in_sizes; (void)n_in; (void)out_size;

    _Float16* qall = qkall;
    _Float16* kall = qkall + (long)4194304;

    // 1. prep: transposes + cvt + zero ctx/attn
    prep_all<<<dim3(10624, 1, 1), 256, 0, stream>>>(
        Wq, Wk, Wv, Wo, queries, keys,
        WqkT, WvT, WoT, a16, ctx, attn_ptr);

    // 2. fused q+k projection (512 blocks) + v projection -> vT (32 blocks)
    qk_vproj<<<dim3(544, 1, 1), 256, 0, stream>>>(
        a16, WqkT, bq, bk, qkall, values, WvT, bv, vT);

    // 3. softmax stats (KVBLK=128)
    attn_stats<<<dim3(16, 16, 4), 256, 0, stream>>>(qall, kall, mbuf, ilbuf);

    // 4. head-mean probabilities + fused PV into ctx
    attn_pmean<<<dim3(16, 16, 4), 256, 0, stream>>>(qall, kall, mbuf, ilbuf, vT, attn_ptr, ctx);

    // 5. out = ctx @ Wo + bo
    gemm_f16_v2<<<dim3(8, 32, 1), 256, 0, stream>>>(
        ctx, nullptr, WoT, bo, nullptr, out_ptr,
        1024, 64, 64, 1024,
        0, 0, 0,
        /*c_half=*/0, /*atomic=*/0, /*nks=*/1, /*kchunk=*/64);
}